// Round 2
// baseline (2091.012 us; speedup 1.0000x reference)
//
#include <hip/hip_runtime.h>
#include <hip/hip_bf16.h>

typedef __bf16 bf16;
typedef __bf16 v8bf __attribute__((ext_vector_type(8)));
typedef float v4f __attribute__((ext_vector_type(4)));

#define NN 100000
#define NE 600000
#define HD 128
#define NG 256

template <int BF> struct WTp;
template <> struct WTp<1> { typedef bf16 T; };
template <> struct WTp<0> { typedef float T; };

static __device__ inline v8bf zero8() {
    v8bf z;
#pragma unroll
    for (int i = 0; i < 8; ++i) z[i] = (bf16)0.f;
    return z;
}

// ---------------- dtype sniff: fp32 N(0,1) data reads in-range; bf16-packed doesn't ----
__global__ void sniff_kernel(const float* __restrict__ xw, int* __restrict__ flag) {
    if (threadIdx.x == 0 && blockIdx.x == 0) {
        int ok = 0;
        for (int i = 0; i < 64; ++i) {
            float v = xw[i];
            float a = fabsf(v);
            if (v == v && a > 1e-8f && a < 1e3f) ok++;
        }
        *flag = (ok >= 48) ? 0 : 1;  // 0 = fp32 world, 1 = bf16 world
    }
}

// ---------------- utility ----------------
__global__ void zero_i32(int* __restrict__ p, int n) {
    int i = blockIdx.x * blockDim.x + threadIdx.x;
    if (i < n) p[i] = 0;
}

// ---------------- CSR build (dtype-independent) ----------------
__global__ void hist_kernel(const int* __restrict__ dst, int* __restrict__ cnt) {
    int e = blockIdx.x * blockDim.x + threadIdx.x;
    if (e < NE) atomicAdd(&cnt[dst[e]], 1);
}

__global__ void scan_part(const int* __restrict__ cnt, int* __restrict__ part) {
    __shared__ int red[256];
    int b = blockIdx.x, t = threadIdx.x;
    int base = b * 1024 + t * 4;
    int s = 0;
#pragma unroll
    for (int q = 0; q < 4; ++q) {
        int i = base + q;
        s += (i < NN) ? cnt[i] : 0;
    }
    red[t] = s;
    __syncthreads();
    for (int off = 128; off > 0; off >>= 1) {
        if (t < off) red[t] += red[t + off];
        __syncthreads();
    }
    if (t == 0) part[b] = red[0];
}

__global__ void scan_small(int* __restrict__ part, int nb, int* __restrict__ rowStart) {
    if (blockIdx.x == 0 && threadIdx.x == 0) {
        int run = 0;
        for (int b = 0; b < nb; ++b) {
            int x = part[b];
            part[b] = run;
            run += x;
        }
        rowStart[NN] = run;  // == NE
    }
}

__global__ void scan_write(const int* __restrict__ cnt, const int* __restrict__ part,
                           int* __restrict__ rowStart, int* __restrict__ cursor) {
    __shared__ int tsum[256];
    int b = blockIdx.x, t = threadIdx.x;
    int base = b * 1024 + t * 4;
    int v[4];
    int s = 0;
#pragma unroll
    for (int q = 0; q < 4; ++q) {
        int i = base + q;
        v[q] = (i < NN) ? cnt[i] : 0;
        s += v[q];
    }
    tsum[t] = s;
    __syncthreads();
    for (int off = 1; off < 256; off <<= 1) {
        int x = (t >= off) ? tsum[t - off] : 0;
        __syncthreads();
        tsum[t] += x;
        __syncthreads();
    }
    int excl = tsum[t] - s + part[b];
#pragma unroll
    for (int q = 0; q < 4; ++q) {
        int i = base + q;
        if (i < NN) {
            rowStart[i] = excl;
            cursor[i] = excl;
            excl += v[q];
        }
    }
}

__global__ void scatter_kernel(const int* __restrict__ src, const int* __restrict__ dst,
                               int* __restrict__ cursor, int* __restrict__ sortedSrc) {
    int e = blockIdx.x * blockDim.x + threadIdx.x;
    if (e < NE) {
        int d = dst[e];
        int pos = atomicAdd(&cursor[d], 1);
        sortedSrc[pos] = src[e];
    }
}

// ---------------- weight transpose (bf16 world only) ----------------
__global__ void transpose128(const int* __restrict__ flag, const bf16* __restrict__ W,
                             bf16* __restrict__ Wt) {
    if (*flag != 1) return;
    int idx = blockIdx.x * blockDim.x + threadIdx.x;  // 0..16383
    int j = idx >> 7, k = idx & 127;
    Wt[j * 128 + k] = W[k * 128 + j];
}

// ---------------- aggregation: hin(buf0) = h + sum_{src->i} h[src] ----------------
template <int BF>
__global__ void agg_t(const int* __restrict__ flag, const void* __restrict__ x_v,
                      char* __restrict__ zone, const int* __restrict__ rowStart,
                      const int* __restrict__ sortedSrc, int layer) {
    if (*flag != BF) return;
    typedef typename WTp<BF>::T T;
    T* buf0 = (T*)zone;
    const T* buf1 = (const T*)(zone + (size_t)NN * HD * sizeof(T));
    const T* hprev = (layer == 0) ? (const T*)x_v : buf1;
    int w = (blockIdx.x * blockDim.x + threadIdx.x) >> 6;  // one wave per node
    int lane = threadIdx.x & 63;
    if (w >= NN) return;
    int s = rowStart[w], e = rowStart[w + 1];
    const T* rp = &hprev[(size_t)w * HD + lane * 2];
    float a0 = (float)rp[0], a1 = (float)rp[1];
    for (int t = s; t < e; ++t) {
        int sn = sortedSrc[t];
        const T* sp = &hprev[(size_t)sn * HD + lane * 2];
        a0 += (float)sp[0];
        a1 += (float)sp[1];
    }
    T* op = &buf0[(size_t)w * HD + lane * 2];
    op[0] = (T)a0;
    op[1] = (T)a1;
}

// ---------------- bf16 fused MLP (MFMA): buf1 = [LN](relu(relu(buf0@W1+b1)@W2+b2)) -----
__global__ __launch_bounds__(256) void mlp_bf16(
    const int* __restrict__ flag, char* __restrict__ zone, const bf16* __restrict__ Wt1,
    const bf16* __restrict__ b1, const bf16* __restrict__ Wt2, const bf16* __restrict__ b2,
    const bf16* __restrict__ gam, const bf16* __restrict__ bet, const int do_ln) {
    if (*flag != 1) return;
    __shared__ bf16 lT[4][16 * 128];  // per-wave intermediate tile (16KB)
    const bf16* hin = (const bf16*)zone;
    bf16* hout = (bf16*)(zone + (size_t)NN * HD * 2);

    const int tid = threadIdx.x;
    const int wave = tid >> 6, lane = tid & 63;
    const int lrow = lane & 15, lg = lane >> 4;
    const int r0 = blockIdx.x * 64 + wave * 16;
    const int arow = r0 + lrow;
    const bool rowok = arow < NN;

    // ---- GEMM1: acc[t] = hin_tile @ W1 ; B fragments straight from global (L2-hot)
    v4f acc[8];
#pragma unroll
    for (int t = 0; t < 8; ++t) acc[t] = (v4f){0.f, 0.f, 0.f, 0.f};
#pragma unroll
    for (int s = 0; s < 4; ++s) {
        v8bf a = rowok ? *(const v8bf*)&hin[(size_t)arow * HD + s * 32 + lg * 8] : zero8();
#pragma unroll
        for (int t = 0; t < 8; ++t) {
            int j = t * 16 + lrow;
            v8bf b = *(const v8bf*)&Wt1[(size_t)j * 128 + s * 32 + lg * 8];
            acc[t] = __builtin_amdgcn_mfma_f32_16x16x32_bf16(a, b, acc[t], 0, 0, 0);
        }
    }
    // ---- bias + relu -> lT (XOR-swizzled to keep GEMM2 A-reads conflict-free)
#pragma unroll
    for (int t = 0; t < 8; ++t) {
        float bj = (float)b1[t * 16 + lrow];
#pragma unroll
        for (int r = 0; r < 4; ++r) {
            float v = fmaxf(acc[t][r] + bj, 0.f);
            int i = lg * 4 + r;          // row within 16-row tile
            int k2 = t * 16 + lrow;      // column (k of GEMM2)
            lT[wave][i * 128 + (((k2 >> 3) ^ i) << 3) + (k2 & 7)] = (bf16)v;
        }
    }
    // ---- GEMM2
    v4f acc2[8];
#pragma unroll
    for (int t = 0; t < 8; ++t) acc2[t] = (v4f){0.f, 0.f, 0.f, 0.f};
#pragma unroll
    for (int s = 0; s < 4; ++s) {
        v8bf a = *(const v8bf*)&lT[wave][lrow * 128 + (((s * 4 + lg) ^ lrow) << 3)];
#pragma unroll
        for (int t = 0; t < 8; ++t) {
            int j = t * 16 + lrow;
            v8bf b = *(const v8bf*)&Wt2[(size_t)j * 128 + s * 32 + lg * 8];
            acc2[t] = __builtin_amdgcn_mfma_f32_16x16x32_bf16(a, b, acc2[t], 0, 0, 0);
        }
    }
    // ---- epilogue: bias + relu (+ LayerNorm) + store
    float vout[8][4];
#pragma unroll
    for (int t = 0; t < 8; ++t) {
        float bj = (float)b2[t * 16 + lrow];
#pragma unroll
        for (int r = 0; r < 4; ++r) vout[t][r] = fmaxf(acc2[t][r] + bj, 0.f);
    }
    if (do_ln) {
        float s1[4] = {0.f, 0.f, 0.f, 0.f}, s2[4] = {0.f, 0.f, 0.f, 0.f};
#pragma unroll
        for (int t = 0; t < 8; ++t)
#pragma unroll
            for (int r = 0; r < 4; ++r) {
                float v = vout[t][r];
                s1[r] += v;
                s2[r] += v * v;
            }
#pragma unroll
        for (int m = 1; m < 16; m <<= 1) {
#pragma unroll
            for (int r = 0; r < 4; ++r) {
                s1[r] += __shfl_xor(s1[r], m, 64);
                s2[r] += __shfl_xor(s2[r], m, 64);
            }
        }
#pragma unroll
        for (int t = 0; t < 8; ++t) {
            float gj = (float)gam[t * 16 + lrow];
            float bb = (float)bet[t * 16 + lrow];
#pragma unroll
            for (int r = 0; r < 4; ++r) {
                float mu = s1[r] * (1.f / 128.f);
                float var = s2[r] * (1.f / 128.f) - mu * mu;
                float rs = rsqrtf(var + 1e-5f);
                vout[t][r] = (vout[t][r] - mu) * rs * gj + bb;
            }
        }
    }
#pragma unroll
    for (int t = 0; t < 8; ++t)
#pragma unroll
        for (int r = 0; r < 4; ++r) {
            int row = r0 + lg * 4 + r;
            if (row < NN) hout[(size_t)row * HD + t * 16 + lrow] = (bf16)vout[t][r];
        }
}

// ---------------- fp32 MLP pass A: buf0 = relu(buf0@W1+b1), in-place ----------------
__global__ __launch_bounds__(256) void mlp_f32_a(const int* __restrict__ flag,
                                                 char* __restrict__ zone,
                                                 const float* __restrict__ W1,
                                                 const float* __restrict__ b1) {
    if (*flag != 0) return;
    __shared__ float lw[128 * 128];  // 64KB, W1 row-major as-is
    float* buf0 = (float*)zone;
    const int tid = threadIdx.x;
    for (int i = tid; i < 4096; i += 256) *(v4f*)&lw[i * 4] = *(const v4f*)&W1[i * 4];
    __syncthreads();
    const int wave = tid >> 6, lane = tid & 63;
    int base = blockIdx.x * 98;
    int rend = base + 98;
    if (rend > NN) rend = NN;
    for (int r = base + wave; r < rend; r += 4) {
        float ha = buf0[(size_t)r * HD + lane];
        float hb = buf0[(size_t)r * HD + 64 + lane];
        float acc0 = b1[lane], acc1 = b1[64 + lane];
#pragma unroll 4
        for (int k = 0; k < 64; ++k) {
            float hk = __shfl(ha, k, 64);
            acc0 += hk * lw[k * 128 + lane];
            acc1 += hk * lw[k * 128 + 64 + lane];
        }
#pragma unroll 4
        for (int k = 0; k < 64; ++k) {
            float hk = __shfl(hb, k, 64);
            acc0 += hk * lw[(64 + k) * 128 + lane];
            acc1 += hk * lw[(64 + k) * 128 + 64 + lane];
        }
        buf0[(size_t)r * HD + lane] = fmaxf(acc0, 0.f);
        buf0[(size_t)r * HD + 64 + lane] = fmaxf(acc1, 0.f);
    }
}

// ---------------- fp32 MLP pass B: buf1 = [LN](relu(buf0@W2+b2)) ----------------
__global__ __launch_bounds__(256) void mlp_f32_b(const int* __restrict__ flag,
                                                 char* __restrict__ zone,
                                                 const float* __restrict__ W2,
                                                 const float* __restrict__ b2,
                                                 const float* __restrict__ gam,
                                                 const float* __restrict__ bet, int do_ln) {
    if (*flag != 0) return;
    __shared__ float lw[128 * 128];
    float* buf0 = (float*)zone;
    float* buf1 = (float*)(zone + (size_t)NN * HD * 4);
    const int tid = threadIdx.x;
    for (int i = tid; i < 4096; i += 256) *(v4f*)&lw[i * 4] = *(const v4f*)&W2[i * 4];
    __syncthreads();
    const int wave = tid >> 6, lane = tid & 63;
    int base = blockIdx.x * 98;
    int rend = base + 98;
    if (rend > NN) rend = NN;
    for (int r = base + wave; r < rend; r += 4) {
        float ha = buf0[(size_t)r * HD + lane];
        float hb = buf0[(size_t)r * HD + 64 + lane];
        float acc0 = b2[lane], acc1 = b2[64 + lane];
#pragma unroll 4
        for (int k = 0; k < 64; ++k) {
            float hk = __shfl(ha, k, 64);
            acc0 += hk * lw[k * 128 + lane];
            acc1 += hk * lw[k * 128 + 64 + lane];
        }
#pragma unroll 4
        for (int k = 0; k < 64; ++k) {
            float hk = __shfl(hb, k, 64);
            acc0 += hk * lw[(64 + k) * 128 + lane];
            acc1 += hk * lw[(64 + k) * 128 + 64 + lane];
        }
        float o0 = fmaxf(acc0, 0.f), o1 = fmaxf(acc1, 0.f);
        if (do_ln) {
            float s = o0 + o1, q = o0 * o0 + o1 * o1;
#pragma unroll
            for (int m = 1; m < 64; m <<= 1) {
                s += __shfl_xor(s, m, 64);
                q += __shfl_xor(q, m, 64);
            }
            float mu = s * (1.f / 128.f);
            float var = q * (1.f / 128.f) - mu * mu;
            float rs = rsqrtf(var + 1e-5f);
            o0 = (o0 - mu) * rs * gam[lane] + bet[lane];
            o1 = (o1 - mu) * rs * gam[64 + lane] + bet[64 + lane];
        }
        buf1[(size_t)r * HD + lane] = o0;
        buf1[(size_t)r * HD + 64 + lane] = o1;
    }
}

// ---------------- mean pool over sorted batch (reads buf1) ----------------
template <int BF>
__global__ void pool_t(const int* __restrict__ flag, char* __restrict__ zone,
                       const int* __restrict__ batch, float* __restrict__ pool,
                       float* __restrict__ cnts) {
    if (*flag != BF) return;
    typedef typename WTp<BF>::T T;
    const T* h = (const T*)(zone + (size_t)NN * HD * sizeof(T));
    int f = threadIdx.x;  // 128 threads
    int n0 = blockIdx.x * 1024;
    int nend = n0 + 1024;
    if (nend > NN) nend = NN;
    int cur = -1;
    float acc = 0.f, c = 0.f;
    for (int n = n0; n < nend; ++n) {
        int g = batch[n];
        if (g != cur) {
            if (cur >= 0) {
                atomicAdd(&pool[cur * HD + f], acc);
                if (f == 0) atomicAdd(&cnts[cur], c);
            }
            cur = g;
            acc = 0.f;
            c = 0.f;
        }
        acc += (float)h[(size_t)n * HD + f];
        c += 1.f;
    }
    if (cur >= 0) {
        atomicAdd(&pool[cur * HD + f], acc);
        if (f == 0) atomicAdd(&cnts[cur], c);
    }
}

// ---------------- head: Linear -> Linear -> log_softmax ----------------
template <int BF>
__global__ void head_t(const int* __restrict__ flag, const float* __restrict__ pool,
                       const float* __restrict__ cnts, const void* __restrict__ Wp1v,
                       const void* __restrict__ bp1v, const void* __restrict__ Wp2v,
                       const void* __restrict__ bp2v, void* __restrict__ outv) {
    if (*flag != BF) return;
    typedef typename WTp<BF>::T T;
    const T* Wp1 = (const T*)Wp1v;
    const T* bp1 = (const T*)bp1v;
    const T* Wp2 = (const T*)Wp2v;
    const T* bp2 = (const T*)bp2v;
    T* out = (T*)outv;
    __shared__ float row[128];
    __shared__ float r0s[128];
    __shared__ float r1s[128];
    int g = blockIdx.x, f = threadIdx.x;
    float c = fmaxf(cnts[g], 1.f);
    row[f] = pool[g * HD + f] / c;
    __syncthreads();
    float p = (float)bp1[f];
    for (int k = 0; k < 128; ++k) p += row[k] * (float)Wp1[k * 128 + f];
    r0s[f] = p * (float)Wp2[f * 2 + 0];
    r1s[f] = p * (float)Wp2[f * 2 + 1];
    __syncthreads();
    for (int off = 64; off > 0; off >>= 1) {
        if (f < off) {
            r0s[f] += r0s[f + off];
            r1s[f] += r1s[f + off];
        }
        __syncthreads();
    }
    if (f == 0) {
        float e0 = r0s[0] + (float)bp2[0];
        float e1 = r1s[0] + (float)bp2[1];
        float m = fmaxf(e0, e1);
        float lse = m + logf(expf(e0 - m) + expf(e1 - m));
        out[g * 2 + 0] = (T)e0;
        out[g * 2 + 1] = (T)e1;
        out[NG * 2 + g * 2 + 0] = (T)(e0 - lse);
        out[NG * 2 + g * 2 + 1] = (T)(e1 - lse);
    }
}

extern "C" void kernel_launch(void* const* d_in, const int* in_sizes, int n_in, void* d_out,
                              int out_size, void* d_ws, size_t ws_size, hipStream_t stream) {
    const void* x = d_in[0];
    const int* ei = (const int*)d_in[1];  // [2][E]: src row then dst row
    const int* batch = (const int*)d_in[2];
    const void* W1[3] = {d_in[3], d_in[7], d_in[11]};
    const void* B1[3] = {d_in[4], d_in[8], d_in[12]};
    const void* W2[3] = {d_in[5], d_in[9], d_in[13]};
    const void* B2[3] = {d_in[6], d_in[10], d_in[14]};
    const void* GAM[2] = {d_in[15], d_in[17]};
    const void* BET[2] = {d_in[16], d_in[18]};

    char* w = (char*)d_ws;
    auto alloc = [&](size_t bytes) {
        void* p = (void*)w;
        w += (bytes + 255) & ~(size_t)255;
        return p;
    };
    int* flag = (int*)alloc(4);
    int* rowStart = (int*)alloc((NN + 1) * 4);
    int* cnt = (int*)alloc(NN * 4);
    int* cursor = (int*)alloc(NN * 4);
    int* part = (int*)alloc(128 * 4);
    float* pool = (float*)alloc(NG * HD * 4 + NG * 4);
    float* cnts = pool + NG * HD;
    bf16* Wt = (bf16*)alloc(6 * 16384 * 2);
    int* sortedSrc = (int*)alloc((size_t)NE * 4);
    char* zone = (char*)alloc((size_t)2 * NN * HD * 4);  // union: fp32 2 bufs / bf16 2 bufs

    const int* srcIdx = ei;
    const int* dstIdx = ei + NE;
    const int NB = (NN + 1023) / 1024;  // 98

    sniff_kernel<<<1, 64, 0, stream>>>((const float*)x, flag);

    // CSR build (dtype-independent)
    zero_i32<<<(NN + 255) / 256, 256, 0, stream>>>(cnt, NN);
    hist_kernel<<<(NE + 255) / 256, 256, 0, stream>>>(dstIdx, cnt);
    scan_part<<<NB, 256, 0, stream>>>(cnt, part);
    scan_small<<<1, 64, 0, stream>>>(part, NB, rowStart);
    scan_write<<<NB, 256, 0, stream>>>(cnt, part, rowStart, cursor);
    scatter_kernel<<<(NE + 255) / 256, 256, 0, stream>>>(srcIdx, dstIdx, cursor, sortedSrc);

    // weight transposes (bf16 world only; flag-guarded)
    for (int l = 0; l < 3; ++l) {
        transpose128<<<64, 256, 0, stream>>>(flag, (const bf16*)W1[l],
                                             Wt + (size_t)(2 * l) * 16384);
        transpose128<<<64, 256, 0, stream>>>(flag, (const bf16*)W2[l],
                                             Wt + (size_t)(2 * l + 1) * 16384);
    }

    // layers
    for (int l = 0; l < 3; ++l) {
        agg_t<1><<<(NN * 64) / 256, 256, 0, stream>>>(flag, x, zone, rowStart, sortedSrc, l);
        agg_t<0><<<(NN * 64) / 256, 256, 0, stream>>>(flag, x, zone, rowStart, sortedSrc, l);
        int doln = (l < 2) ? 1 : 0;
        const void* g = (l < 2) ? GAM[l] : GAM[0];
        const void* be = (l < 2) ? BET[l] : BET[0];
        mlp_bf16<<<(NN + 63) / 64, 256, 0, stream>>>(
            flag, zone, Wt + (size_t)(2 * l) * 16384, (const bf16*)B1[l],
            Wt + (size_t)(2 * l + 1) * 16384, (const bf16*)B2[l], (const bf16*)g,
            (const bf16*)be, doln);
        mlp_f32_a<<<1024, 256, 0, stream>>>(flag, zone, (const float*)W1[l],
                                            (const float*)B1[l]);
        mlp_f32_b<<<1024, 256, 0, stream>>>(flag, zone, (const float*)W2[l],
                                            (const float*)B2[l], (const float*)g,
                                            (const float*)be, doln);
    }

    // pooling + head
    zero_i32<<<(NG * 129 + 255) / 256, 256, 0, stream>>>((int*)pool, NG * 129);
    pool_t<1><<<NB, 128, 0, stream>>>(flag, zone, batch, pool, cnts);
    pool_t<0><<<NB, 128, 0, stream>>>(flag, zone, batch, pool, cnts);
    head_t<1><<<NG, 128, 0, stream>>>(flag, pool, cnts, d_in[19], d_in[20], d_in[21], d_in[22],
                                      d_out);
    head_t<0><<<NG, 128, 0, stream>>>(flag, pool, cnts, d_in[19], d_in[20], d_in[21], d_in[22],
                                      d_out);
}

// Round 4
// 470.727 us; speedup vs baseline: 4.4421x; 4.4421x over previous
//
#include <hip/hip_runtime.h>
#include <hip/hip_bf16.h>

typedef __bf16 bf16;
typedef __bf16 v2bf __attribute__((ext_vector_type(2)));
typedef __bf16 v8bf __attribute__((ext_vector_type(8)));
typedef float v4f __attribute__((ext_vector_type(4)));

#define NN 100000
#define NE 600000
#define HD 128
#define NG 256

static __device__ inline v8bf zero8() {
    v8bf z;
#pragma unroll
    for (int i = 0; i < 8; ++i) z[i] = (bf16)0.f;
    return z;
}

// ---------------- utility ----------------
__global__ void zero_i32(int* __restrict__ p, int n) {
    int i = blockIdx.x * blockDim.x + threadIdx.x;
    if (i < n) p[i] = 0;
}

// ---------------- fp32 -> bf16 convert (x only) ----------------
__global__ void conv_kernel(const float* __restrict__ x, bf16* __restrict__ xb) {
    int i = blockIdx.x * blockDim.x + threadIdx.x;  // one per 8 elems
    const v4f a = *(const v4f*)&x[(size_t)i * 8];
    const v4f b = *(const v4f*)&x[(size_t)i * 8 + 4];
    v8bf o;
#pragma unroll
    for (int q = 0; q < 4; ++q) {
        o[q] = (bf16)a[q];
        o[4 + q] = (bf16)b[q];
    }
    *(v8bf*)&xb[(size_t)i * 8] = o;
}

// ---------------- CSR build ----------------
__global__ void hist_kernel(const int* __restrict__ dst, int* __restrict__ cnt) {
    int e = blockIdx.x * blockDim.x + threadIdx.x;
    if (e < NE) atomicAdd(&cnt[dst[e]], 1);
}

__global__ void scan_part(const int* __restrict__ cnt, int* __restrict__ part) {
    __shared__ int red[256];
    int b = blockIdx.x, t = threadIdx.x;
    int base = b * 1024 + t * 4;
    int s = 0;
#pragma unroll
    for (int q = 0; q < 4; ++q) {
        int i = base + q;
        s += (i < NN) ? cnt[i] : 0;
    }
    red[t] = s;
    __syncthreads();
    for (int off = 128; off > 0; off >>= 1) {
        if (t < off) red[t] += red[t + off];
        __syncthreads();
    }
    if (t == 0) part[b] = red[0];
}

__global__ void scan_small(int* __restrict__ part, int nb, int* __restrict__ rowStart) {
    if (blockIdx.x == 0 && threadIdx.x == 0) {
        int run = 0;
        for (int b = 0; b < nb; ++b) {
            int x = part[b];
            part[b] = run;
            run += x;
        }
        rowStart[NN] = run;  // == NE
    }
}

__global__ void scan_write(const int* __restrict__ cnt, const int* __restrict__ part,
                           int* __restrict__ rowStart, int* __restrict__ cursor) {
    __shared__ int tsum[256];
    int b = blockIdx.x, t = threadIdx.x;
    int base = b * 1024 + t * 4;
    int v[4];
    int s = 0;
#pragma unroll
    for (int q = 0; q < 4; ++q) {
        int i = base + q;
        v[q] = (i < NN) ? cnt[i] : 0;
        s += v[q];
    }
    tsum[t] = s;
    __syncthreads();
    for (int off = 1; off < 256; off <<= 1) {
        int x = (t >= off) ? tsum[t - off] : 0;
        __syncthreads();
        tsum[t] += x;
        __syncthreads();
    }
    int excl = tsum[t] - s + part[b];
#pragma unroll
    for (int q = 0; q < 4; ++q) {
        int i = base + q;
        if (i < NN) {
            rowStart[i] = excl;
            cursor[i] = excl;
            excl += v[q];
        }
    }
}

__global__ void scatter_kernel(const int* __restrict__ src, const int* __restrict__ dst,
                               int* __restrict__ cursor, int* __restrict__ sortedSrc) {
    int e = blockIdx.x * blockDim.x + threadIdx.x;
    if (e < NE) {
        int d = dst[e];
        int pos = atomicAdd(&cursor[d], 1);
        sortedSrc[pos] = src[e];
    }
}

// ---------------- weight transpose + fp32->bf16 (128x128) ----------------
__global__ void transpose128(const float* __restrict__ W, bf16* __restrict__ Wt) {
    int idx = blockIdx.x * blockDim.x + threadIdx.x;  // 0..16383
    int j = idx >> 7, k = idx & 127;
    Wt[j * 128 + k] = (bf16)W[k * 128 + j];
}

// ---------------- graph boundaries from sorted batch ----------------
__global__ void bounds_kernel(const int* __restrict__ batch, int* __restrict__ gstart) {
    int n = blockIdx.x * blockDim.x + threadIdx.x;
    if (n >= NN) return;
    int b = batch[n];
    int prev = (n == 0) ? -1 : batch[n - 1];
    for (int g = prev + 1; g <= b; ++g) gstart[g] = n;
    if (n == NN - 1)
        for (int g = b + 1; g <= NG; ++g) gstart[g] = NN;
}

// ---------------- aggregation: hin = h + sum_{src->i} h[src] ----------------
// one wave per node; indices loaded coalesced & broadcast via shfl
__global__ void agg_kernel(const bf16* __restrict__ hprev, const int* __restrict__ rowStart,
                           const int* __restrict__ sortedSrc, bf16* __restrict__ hin) {
    int w = (blockIdx.x * blockDim.x + threadIdx.x) >> 6;
    int lane = threadIdx.x & 63;
    if (w >= NN) return;
    int s = rowStart[w], e = rowStart[w + 1];
    v2bf h = *(const v2bf*)&hprev[(size_t)w * HD + lane * 2];
    float a0 = (float)h[0], a1 = (float)h[1];
    for (int base = s; base < e; base += 64) {
        int cnt = e - base;
        if (cnt > 64) cnt = 64;
        int idx = (lane < cnt) ? sortedSrc[base + lane] : 0;
        for (int i = 0; i < cnt; ++i) {
            int sn = __shfl(idx, i, 64);
            v2bf xx = *(const v2bf*)&hprev[(size_t)sn * HD + lane * 2];
            a0 += (float)xx[0];
            a1 += (float)xx[1];
        }
    }
    v2bf o;
    o[0] = (bf16)a0;
    o[1] = (bf16)a1;
    *(v2bf*)&hin[(size_t)w * HD + lane * 2] = o;
}

// ---------------- fused MLP: hout = [LN](relu(relu(hin@W1+b1)@W2+b2)) ----------------
__global__ __launch_bounds__(256) void mlp_bf16(const bf16* __restrict__ hin,
                                                const bf16* __restrict__ Wt1,
                                                const float* __restrict__ b1,
                                                const bf16* __restrict__ Wt2,
                                                const float* __restrict__ b2,
                                                const float* __restrict__ gam,
                                                const float* __restrict__ bet, const int do_ln,
                                                bf16* __restrict__ hout) {
    __shared__ bf16 lT[4][16 * 128];  // per-wave intermediate tile (16KB)
    const int tid = threadIdx.x;
    const int wave = tid >> 6, lane = tid & 63;
    const int lrow = lane & 15, lg = lane >> 4;
    const int r0 = blockIdx.x * 64 + wave * 16;
    const int arow = r0 + lrow;
    const bool rowok = arow < NN;

    // ---- GEMM1: acc[t] = hin_tile @ W1 ; B fragments from global (L2-hot weights)
    v4f acc[8];
#pragma unroll
    for (int t = 0; t < 8; ++t) acc[t] = (v4f){0.f, 0.f, 0.f, 0.f};
#pragma unroll
    for (int s = 0; s < 4; ++s) {
        v8bf a = rowok ? *(const v8bf*)&hin[(size_t)arow * HD + s * 32 + lg * 8] : zero8();
#pragma unroll
        for (int t = 0; t < 8; ++t) {
            int j = t * 16 + lrow;
            v8bf b = *(const v8bf*)&Wt1[(size_t)j * 128 + s * 32 + lg * 8];
            acc[t] = __builtin_amdgcn_mfma_f32_16x16x32_bf16(a, b, acc[t], 0, 0, 0);
        }
    }
    // ---- bias + relu -> lT (XOR-swizzled for conflict-free GEMM2 A-reads)
#pragma unroll
    for (int t = 0; t < 8; ++t) {
        float bj = b1[t * 16 + lrow];
#pragma unroll
        for (int r = 0; r < 4; ++r) {
            float v = fmaxf(acc[t][r] + bj, 0.f);
            int i = lg * 4 + r;
            int k2 = t * 16 + lrow;
            lT[wave][i * 128 + (((k2 >> 3) ^ i) << 3) + (k2 & 7)] = (bf16)v;
        }
    }
    // ---- GEMM2
    v4f acc2[8];
#pragma unroll
    for (int t = 0; t < 8; ++t) acc2[t] = (v4f){0.f, 0.f, 0.f, 0.f};
#pragma unroll
    for (int s = 0; s < 4; ++s) {
        v8bf a = *(const v8bf*)&lT[wave][lrow * 128 + (((s * 4 + lg) ^ lrow) << 3)];
#pragma unroll
        for (int t = 0; t < 8; ++t) {
            int j = t * 16 + lrow;
            v8bf b = *(const v8bf*)&Wt2[(size_t)j * 128 + s * 32 + lg * 8];
            acc2[t] = __builtin_amdgcn_mfma_f32_16x16x32_bf16(a, b, acc2[t], 0, 0, 0);
        }
    }
    // ---- epilogue: bias + relu (+ LN) + store
    float vout[8][4];
#pragma unroll
    for (int t = 0; t < 8; ++t) {
        float bj = b2[t * 16 + lrow];
#pragma unroll
        for (int r = 0; r < 4; ++r) vout[t][r] = fmaxf(acc2[t][r] + bj, 0.f);
    }
    if (do_ln) {
        float s1[4] = {0.f, 0.f, 0.f, 0.f}, s2[4] = {0.f, 0.f, 0.f, 0.f};
#pragma unroll
        for (int t = 0; t < 8; ++t)
#pragma unroll
            for (int r = 0; r < 4; ++r) {
                float v = vout[t][r];
                s1[r] += v;
                s2[r] += v * v;
            }
#pragma unroll
        for (int m = 1; m < 16; m <<= 1) {
#pragma unroll
            for (int r = 0; r < 4; ++r) {
                s1[r] += __shfl_xor(s1[r], m, 64);
                s2[r] += __shfl_xor(s2[r], m, 64);
            }
        }
#pragma unroll
        for (int t = 0; t < 8; ++t) {
            float gj = gam[t * 16 + lrow];
            float bb = bet[t * 16 + lrow];
#pragma unroll
            for (int r = 0; r < 4; ++r) {
                float mu = s1[r] * (1.f / 128.f);
                float var = s2[r] * (1.f / 128.f) - mu * mu;
                float rs = rsqrtf(var + 1e-5f);
                vout[t][r] = (vout[t][r] - mu) * rs * gj + bb;
            }
        }
    }
#pragma unroll
    for (int t = 0; t < 8; ++t)
#pragma unroll
        for (int r = 0; r < 4; ++r) {
            int row = r0 + lg * 4 + r;
            if (row < NN) hout[(size_t)row * HD + t * 16 + lrow] = (bf16)vout[t][r];
        }
}

// ---------------- mean pool: one block per graph, streaming, no atomics ----------------
__global__ void pool_g(const bf16* __restrict__ h, const int* __restrict__ gstart,
                       float* __restrict__ pooled) {
    int g = blockIdx.x, f = threadIdx.x;  // 128 threads
    int gs = gstart[g], ge = gstart[g + 1];
    float acc = 0.f;
    int n = gs;
#pragma unroll 1
    for (; n + 4 <= ge; n += 4) {
        float a0 = (float)h[(size_t)(n + 0) * HD + f];
        float a1 = (float)h[(size_t)(n + 1) * HD + f];
        float a2 = (float)h[(size_t)(n + 2) * HD + f];
        float a3 = (float)h[(size_t)(n + 3) * HD + f];
        acc += (a0 + a1) + (a2 + a3);
    }
    for (; n < ge; ++n) acc += (float)h[(size_t)n * HD + f];
    float c = (float)(ge - gs);
    pooled[g * HD + f] = acc / fmaxf(c, 1.f);
}

// ---------------- head: Linear -> Linear -> log_softmax (all fp32) ----------------
__global__ void head_kernel(const float* __restrict__ pooled, const float* __restrict__ Wp1,
                            const float* __restrict__ bp1, const float* __restrict__ Wp2,
                            const float* __restrict__ bp2, float* __restrict__ out) {
    __shared__ float row[128];
    __shared__ float r0s[128];
    __shared__ float r1s[128];
    int g = blockIdx.x, f = threadIdx.x;
    row[f] = pooled[g * HD + f];
    __syncthreads();
    float p = bp1[f];
    for (int k = 0; k < 128; ++k) p += row[k] * Wp1[k * 128 + f];
    r0s[f] = p * Wp2[f * 2 + 0];
    r1s[f] = p * Wp2[f * 2 + 1];
    __syncthreads();
    for (int off = 64; off > 0; off >>= 1) {
        if (f < off) {
            r0s[f] += r0s[f + off];
            r1s[f] += r1s[f + off];
        }
        __syncthreads();
    }
    if (f == 0) {
        float e0 = r0s[0] + bp2[0];
        float e1 = r1s[0] + bp2[1];
        float m = fmaxf(e0, e1);
        float lse = m + logf(expf(e0 - m) + expf(e1 - m));
        out[g * 2 + 0] = e0;
        out[g * 2 + 1] = e1;
        out[NG * 2 + g * 2 + 0] = e0 - lse;
        out[NG * 2 + g * 2 + 1] = e1 - lse;
    }
}

extern "C" void kernel_launch(void* const* d_in, const int* in_sizes, int n_in, void* d_out,
                              int out_size, void* d_ws, size_t ws_size, hipStream_t stream) {
    const float* x = (const float*)d_in[0];
    const int* ei = (const int*)d_in[1];  // [2][E]: src row then dst row
    const int* batch = (const int*)d_in[2];
    const float* W1[3] = {(const float*)d_in[3], (const float*)d_in[7], (const float*)d_in[11]};
    const float* B1[3] = {(const float*)d_in[4], (const float*)d_in[8], (const float*)d_in[12]};
    const float* W2[3] = {(const float*)d_in[5], (const float*)d_in[9], (const float*)d_in[13]};
    const float* B2[3] = {(const float*)d_in[6], (const float*)d_in[10], (const float*)d_in[14]};
    const float* GAM[2] = {(const float*)d_in[15], (const float*)d_in[17]};
    const float* BET[2] = {(const float*)d_in[16], (const float*)d_in[18]};
    const float* Wp1 = (const float*)d_in[19];
    const float* bp1 = (const float*)d_in[20];
    const float* Wp2 = (const float*)d_in[21];
    const float* bp2 = (const float*)d_in[22];

    char* w = (char*)d_ws;
    auto alloc = [&](size_t bytes) {
        void* p = (void*)w;
        w += (bytes + 255) & ~(size_t)255;
        return p;
    };
    int* rowStart = (int*)alloc((NN + 1) * 4);
    int* cnt = (int*)alloc(NN * 4);
    int* cursor = (int*)alloc(NN * 4);
    int* part = (int*)alloc(128 * 4);
    int* gstart = (int*)alloc((NG + 1) * 4);
    float* pooled = (float*)alloc(NG * HD * 4);
    bf16* Wt = (bf16*)alloc(6 * 16384 * 2);
    int* sortedSrc = (int*)alloc((size_t)NE * 4);
    bf16* xb = (bf16*)alloc((size_t)NN * HD * 2);
    bf16* bufT = (bf16*)alloc((size_t)NN * HD * 2);
    bf16* bufH = (bf16*)alloc((size_t)NN * HD * 2);

    const int* srcIdx = ei;
    const int* dstIdx = ei + NE;
    const int NB = (NN + 1023) / 1024;  // 98

    // x -> bf16
    conv_kernel<<<(NN * HD / 8) / 256, 256, 0, stream>>>(x, xb);  // 6250 blocks

    // CSR build
    zero_i32<<<(NN + 255) / 256, 256, 0, stream>>>(cnt, NN);
    hist_kernel<<<(NE + 255) / 256, 256, 0, stream>>>(dstIdx, cnt);
    scan_part<<<NB, 256, 0, stream>>>(cnt, part);
    scan_small<<<1, 64, 0, stream>>>(part, NB, rowStart);
    scan_write<<<NB, 256, 0, stream>>>(cnt, part, rowStart, cursor);
    scatter_kernel<<<(NE + 255) / 256, 256, 0, stream>>>(srcIdx, dstIdx, cursor, sortedSrc);

    // graph boundaries + weight transposes (fp32 -> bf16)
    bounds_kernel<<<(NN + 255) / 256, 256, 0, stream>>>(batch, gstart);
    for (int l = 0; l < 3; ++l) {
        transpose128<<<64, 256, 0, stream>>>(W1[l], Wt + (size_t)(2 * l) * 16384);
        transpose128<<<64, 256, 0, stream>>>(W2[l], Wt + (size_t)(2 * l + 1) * 16384);
    }

    // layers
    const bf16* hp = xb;
    for (int l = 0; l < 3; ++l) {
        agg_kernel<<<(NN * 64) / 256, 256, 0, stream>>>(hp, rowStart, sortedSrc, bufT);
        int doln = (l < 2) ? 1 : 0;
        const float* g = (l < 2) ? GAM[l] : GAM[0];
        const float* be = (l < 2) ? BET[l] : BET[0];
        mlp_bf16<<<(NN + 63) / 64, 256, 0, stream>>>(bufT, Wt + (size_t)(2 * l) * 16384, B1[l],
                                                     Wt + (size_t)(2 * l + 1) * 16384, B2[l], g,
                                                     be, doln, bufH);
        hp = bufH;
    }

    // pooling + head
    pool_g<<<NG, 128, 0, stream>>>(bufH, gstart, pooled);
    head_kernel<<<NG, 128, 0, stream>>>(pooled, Wp1, bp1, Wp2, bp2, (float*)d_out);
}

// Round 5
// 318.716 us; speedup vs baseline: 6.5607x; 1.4769x over previous
//
#include <hip/hip_runtime.h>
#include <hip/hip_bf16.h>

typedef __bf16 bf16;
typedef __bf16 v8bf __attribute__((ext_vector_type(8)));
typedef float v4f __attribute__((ext_vector_type(4)));

#define NN 100000
#define NE 600000
#define HD 128
#define NG 256
#define NCHUNK ((NN + 63) / 64)  // 1563

static __device__ inline v8bf zero8() {
    v8bf z;
#pragma unroll
    for (int i = 0; i < 8; ++i) z[i] = (bf16)0.f;
    return z;
}

// ---------------- utility ----------------
__global__ void zero_i32(int* __restrict__ p, int n) {
    int i = blockIdx.x * blockDim.x + threadIdx.x;
    if (i < n) p[i] = 0;
}

// ---------------- fp32 -> bf16 convert (x only) ----------------
__global__ void conv_kernel(const float* __restrict__ x, bf16* __restrict__ xb) {
    int i = blockIdx.x * blockDim.x + threadIdx.x;  // one per 8 elems
    const v4f a = *(const v4f*)&x[(size_t)i * 8];
    const v4f b = *(const v4f*)&x[(size_t)i * 8 + 4];
    v8bf o;
#pragma unroll
    for (int q = 0; q < 4; ++q) {
        o[q] = (bf16)a[q];
        o[4 + q] = (bf16)b[q];
    }
    *(v8bf*)&xb[(size_t)i * 8] = o;
}

// ---------------- CSR build ----------------
__global__ void hist_kernel(const int* __restrict__ dst, int* __restrict__ cnt) {
    int e = blockIdx.x * blockDim.x + threadIdx.x;
    if (e < NE) atomicAdd(&cnt[dst[e]], 1);
}

__global__ void scan_part(const int* __restrict__ cnt, int* __restrict__ part) {
    __shared__ int red[256];
    int b = blockIdx.x, t = threadIdx.x;
    int base = b * 1024 + t * 4;
    int s = 0;
#pragma unroll
    for (int q = 0; q < 4; ++q) {
        int i = base + q;
        s += (i < NN) ? cnt[i] : 0;
    }
    red[t] = s;
    __syncthreads();
    for (int off = 128; off > 0; off >>= 1) {
        if (t < off) red[t] += red[t + off];
        __syncthreads();
    }
    if (t == 0) part[b] = red[0];
}

__global__ void scan_small(int* __restrict__ part, int nb, int* __restrict__ rowStart) {
    if (blockIdx.x == 0 && threadIdx.x == 0) {
        int run = 0;
        for (int b = 0; b < nb; ++b) {
            int x = part[b];
            part[b] = run;
            run += x;
        }
        rowStart[NN] = run;  // == NE
    }
}

__global__ void scan_write(const int* __restrict__ cnt, const int* __restrict__ part,
                           int* __restrict__ rowStart, int* __restrict__ cursor) {
    __shared__ int tsum[256];
    int b = blockIdx.x, t = threadIdx.x;
    int base = b * 1024 + t * 4;
    int v[4];
    int s = 0;
#pragma unroll
    for (int q = 0; q < 4; ++q) {
        int i = base + q;
        v[q] = (i < NN) ? cnt[i] : 0;
        s += v[q];
    }
    tsum[t] = s;
    __syncthreads();
    for (int off = 1; off < 256; off <<= 1) {
        int x = (t >= off) ? tsum[t - off] : 0;
        __syncthreads();
        tsum[t] += x;
        __syncthreads();
    }
    int excl = tsum[t] - s + part[b];
#pragma unroll
    for (int q = 0; q < 4; ++q) {
        int i = base + q;
        if (i < NN) {
            rowStart[i] = excl;
            cursor[i] = excl;
            excl += v[q];
        }
    }
}

__global__ void scatter_kernel(const int* __restrict__ src, const int* __restrict__ dst,
                               int* __restrict__ cursor, int* __restrict__ sortedSrc) {
    int e = blockIdx.x * blockDim.x + threadIdx.x;
    if (e < NE) {
        int d = dst[e];
        int pos = atomicAdd(&cursor[d], 1);
        sortedSrc[pos] = src[e];
    }
}

// ------- weight prep: W (fp32, row-major [k][j]) -> W^T bf16, XOR-swizzled -------
// element (j,k) of W^T stored at j*128 + ((ck ^ (j&15))<<3) + (k&7), ck=k>>3.
// A linear LDS copy of this array preserves the swizzle.
__global__ void wprep(const float* __restrict__ W, bf16* __restrict__ Wsw) {
    int c = blockIdx.x * blockDim.x + threadIdx.x;  // 0..2047
    int j = c >> 4, ck = c & 15;
    v8bf o;
#pragma unroll
    for (int q = 0; q < 8; ++q) o[q] = (bf16)W[(ck * 8 + q) * 128 + j];
    *(v8bf*)&Wsw[j * 128 + ((ck ^ (j & 15)) << 3)] = o;
}

// ---------------- graph boundaries from sorted batch ----------------
__global__ void bounds_kernel(const int* __restrict__ batch, int* __restrict__ gstart) {
    int n = blockIdx.x * blockDim.x + threadIdx.x;
    if (n >= NN) return;
    int b = batch[n];
    int prev = (n == 0) ? -1 : batch[n - 1];
    for (int g = prev + 1; g <= b; ++g) gstart[g] = n;
    if (n == NN - 1)
        for (int g = b + 1; g <= NG; ++g) gstart[g] = NN;
}

// ---------------- aggregation: hin = h + sum_{src->i} h[src] ----------------
// 4 nodes per wave: each 16-lane group owns one node, 16B per lane.
// Indices loaded coalesced per group, broadcast via shfl.
__global__ void agg_kernel(const bf16* __restrict__ hprev, const int* __restrict__ rowStart,
                           const int* __restrict__ sortedSrc, bf16* __restrict__ hin) {
    int node = (blockIdx.x * blockDim.x + threadIdx.x) >> 4;
    if (node >= NN) return;
    int l16 = threadIdx.x & 15;
    int grp = (threadIdx.x & 63) >> 4;  // group within wave
    int s = rowStart[node], e = rowStart[node + 1];
    v8bf h = *(const v8bf*)&hprev[(size_t)node * HD + l16 * 8];
    float a[8];
#pragma unroll
    for (int q = 0; q < 8; ++q) a[q] = (float)h[q];
    for (int base = s; base < e; base += 16) {
        int cnt = e - base;
        if (cnt > 16) cnt = 16;
        int idx = (l16 < cnt) ? sortedSrc[base + l16] : 0;
        for (int i = 0; i < cnt; ++i) {
            int sn = __shfl(idx, grp * 16 + i, 64);
            v8bf xx = *(const v8bf*)&hprev[(size_t)sn * HD + l16 * 8];
#pragma unroll
            for (int q = 0; q < 8; ++q) a[q] += (float)xx[q];
        }
    }
    v8bf o;
#pragma unroll
    for (int q = 0; q < 8; ++q) o[q] = (bf16)a[q];
    *(v8bf*)&hin[(size_t)node * HD + l16 * 8] = o;
}

// -------- fused MLP v2: persistent blocks, weights staged once in LDS --------
__global__ __launch_bounds__(256) void mlp_bf16(const bf16* __restrict__ hin,
                                                const bf16* __restrict__ W1s,
                                                const float* __restrict__ b1,
                                                const bf16* __restrict__ W2s,
                                                const float* __restrict__ b2,
                                                const float* __restrict__ gam,
                                                const float* __restrict__ bet, const int do_ln,
                                                bf16* __restrict__ hout) {
    __shared__ bf16 lw[2][128 * 128];  // swizzled W1^T, W2^T (64KB)
    __shared__ bf16 lT[4][16 * 128];   // per-wave intermediate tile (16KB)

    const int tid = threadIdx.x;
    // stage both weights (linear copy of pre-swizzled arrays)
    for (int i = tid; i < 2048; i += 256) {
        *(v8bf*)&lw[0][i * 8] = *(const v8bf*)&W1s[i * 8];
        *(v8bf*)&lw[1][i * 8] = *(const v8bf*)&W2s[i * 8];
    }
    __syncthreads();

    const int wave = tid >> 6, lane = tid & 63;
    const int lrow = lane & 15, lg = lane >> 4;

    // hoist per-thread epilogue constants
    float bj1[8], bj2[8], gj[8], bb[8];
#pragma unroll
    for (int t = 0; t < 8; ++t) {
        bj1[t] = b1[t * 16 + lrow];
        bj2[t] = b2[t * 16 + lrow];
        gj[t] = gam[t * 16 + lrow];
        bb[t] = bet[t * 16 + lrow];
    }

    for (int chunk = blockIdx.x; chunk < NCHUNK; chunk += gridDim.x) {
        const int r0 = chunk * 64 + wave * 16;
        const int arow = r0 + lrow;
        const bool rowok = arow < NN;

        // ---- GEMM1: acc[t] = hin_tile @ W1 (B fragments from LDS)
        v4f acc[8];
#pragma unroll
        for (int t = 0; t < 8; ++t) acc[t] = (v4f){0.f, 0.f, 0.f, 0.f};
#pragma unroll
        for (int s = 0; s < 4; ++s) {
            v8bf a = rowok ? *(const v8bf*)&hin[(size_t)arow * HD + s * 32 + lg * 8] : zero8();
#pragma unroll
            for (int t = 0; t < 8; ++t) {
                int j = t * 16 + lrow;
                v8bf b = *(const v8bf*)&lw[0][j * 128 + (((s * 4 + lg) ^ (j & 15)) << 3)];
                acc[t] = __builtin_amdgcn_mfma_f32_16x16x32_bf16(a, b, acc[t], 0, 0, 0);
            }
        }
        // ---- bias + relu -> lT (XOR-swizzled for conflict-free GEMM2 A-reads)
#pragma unroll
        for (int t = 0; t < 8; ++t) {
#pragma unroll
            for (int r = 0; r < 4; ++r) {
                float v = fmaxf(acc[t][r] + bj1[t], 0.f);
                int i = lg * 4 + r;
                int k2 = t * 16 + lrow;
                lT[wave][i * 128 + (((k2 >> 3) ^ i) << 3) + (k2 & 7)] = (bf16)v;
            }
        }
        // ---- GEMM2
        v4f acc2[8];
#pragma unroll
        for (int t = 0; t < 8; ++t) acc2[t] = (v4f){0.f, 0.f, 0.f, 0.f};
#pragma unroll
        for (int s = 0; s < 4; ++s) {
            v8bf a = *(const v8bf*)&lT[wave][lrow * 128 + (((s * 4 + lg) ^ lrow) << 3)];
#pragma unroll
            for (int t = 0; t < 8; ++t) {
                int j = t * 16 + lrow;
                v8bf b = *(const v8bf*)&lw[1][j * 128 + (((s * 4 + lg) ^ (j & 15)) << 3)];
                acc2[t] = __builtin_amdgcn_mfma_f32_16x16x32_bf16(a, b, acc2[t], 0, 0, 0);
            }
        }
        // ---- epilogue: bias + relu (+ LN) + store
        float vout[8][4];
#pragma unroll
        for (int t = 0; t < 8; ++t) {
#pragma unroll
            for (int r = 0; r < 4; ++r) vout[t][r] = fmaxf(acc2[t][r] + bj2[t], 0.f);
        }
        if (do_ln) {
            float s1[4] = {0.f, 0.f, 0.f, 0.f}, s2[4] = {0.f, 0.f, 0.f, 0.f};
#pragma unroll
            for (int t = 0; t < 8; ++t)
#pragma unroll
                for (int r = 0; r < 4; ++r) {
                    float v = vout[t][r];
                    s1[r] += v;
                    s2[r] += v * v;
                }
#pragma unroll
            for (int m = 1; m < 16; m <<= 1) {
#pragma unroll
                for (int r = 0; r < 4; ++r) {
                    s1[r] += __shfl_xor(s1[r], m, 64);
                    s2[r] += __shfl_xor(s2[r], m, 64);
                }
            }
#pragma unroll
            for (int t = 0; t < 8; ++t) {
#pragma unroll
                for (int r = 0; r < 4; ++r) {
                    float mu = s1[r] * (1.f / 128.f);
                    float var = s2[r] * (1.f / 128.f) - mu * mu;
                    float rs = rsqrtf(var + 1e-5f);
                    vout[t][r] = (vout[t][r] - mu) * rs * gj[t] + bb[t];
                }
            }
        }
#pragma unroll
        for (int t = 0; t < 8; ++t)
#pragma unroll
            for (int r = 0; r < 4; ++r) {
                int row = r0 + lg * 4 + r;
                if (row < NN) hout[(size_t)row * HD + t * 16 + lrow] = (bf16)vout[t][r];
            }
    }
}

// ---------------- mean pool: one block per graph, 256 threads ----------------
__global__ void pool_g(const bf16* __restrict__ h, const int* __restrict__ gstart,
                       float* __restrict__ pooled) {
    __shared__ float part[128];
    int g = blockIdx.x;
    int f = threadIdx.x & 127, half = threadIdx.x >> 7;  // 0/1
    int gs = gstart[g], ge = gstart[g + 1];
    float acc = 0.f;
    int n = gs + half;
#pragma unroll 1
    for (; n + 6 < ge; n += 8) {
        float a0 = (float)h[(size_t)(n + 0) * HD + f];
        float a1 = (float)h[(size_t)(n + 2) * HD + f];
        float a2 = (float)h[(size_t)(n + 4) * HD + f];
        float a3 = (float)h[(size_t)(n + 6) * HD + f];
        acc += (a0 + a1) + (a2 + a3);
    }
    for (; n < ge; n += 2) acc += (float)h[(size_t)n * HD + f];
    if (half == 1) part[f] = acc;
    __syncthreads();
    if (half == 0) {
        float tot = acc + part[f];
        float c = (float)(ge - gs);
        pooled[g * HD + f] = tot / fmaxf(c, 1.f);
    }
}

// ---------------- head: Linear -> Linear -> log_softmax (all fp32) ----------------
__global__ void head_kernel(const float* __restrict__ pooled, const float* __restrict__ Wp1,
                            const float* __restrict__ bp1, const float* __restrict__ Wp2,
                            const float* __restrict__ bp2, float* __restrict__ out) {
    __shared__ float row[128];
    __shared__ float r0s[128];
    __shared__ float r1s[128];
    int g = blockIdx.x, f = threadIdx.x;
    row[f] = pooled[g * HD + f];
    __syncthreads();
    float p = bp1[f];
    for (int k = 0; k < 128; ++k) p += row[k] * Wp1[k * 128 + f];
    r0s[f] = p * Wp2[f * 2 + 0];
    r1s[f] = p * Wp2[f * 2 + 1];
    __syncthreads();
    for (int off = 64; off > 0; off >>= 1) {
        if (f < off) {
            r0s[f] += r0s[f + off];
            r1s[f] += r1s[f + off];
        }
        __syncthreads();
    }
    if (f == 0) {
        float e0 = r0s[0] + bp2[0];
        float e1 = r1s[0] + bp2[1];
        float m = fmaxf(e0, e1);
        float lse = m + logf(expf(e0 - m) + expf(e1 - m));
        out[g * 2 + 0] = e0;
        out[g * 2 + 1] = e1;
        out[NG * 2 + g * 2 + 0] = e0 - lse;
        out[NG * 2 + g * 2 + 1] = e1 - lse;
    }
}

extern "C" void kernel_launch(void* const* d_in, const int* in_sizes, int n_in, void* d_out,
                              int out_size, void* d_ws, size_t ws_size, hipStream_t stream) {
    const float* x = (const float*)d_in[0];
    const int* ei = (const int*)d_in[1];  // [2][E]: src row then dst row
    const int* batch = (const int*)d_in[2];
    const float* W1[3] = {(const float*)d_in[3], (const float*)d_in[7], (const float*)d_in[11]};
    const float* B1[3] = {(const float*)d_in[4], (const float*)d_in[8], (const float*)d_in[12]};
    const float* W2[3] = {(const float*)d_in[5], (const float*)d_in[9], (const float*)d_in[13]};
    const float* B2[3] = {(const float*)d_in[6], (const float*)d_in[10], (const float*)d_in[14]};
    const float* GAM[2] = {(const float*)d_in[15], (const float*)d_in[17]};
    const float* BET[2] = {(const float*)d_in[16], (const float*)d_in[18]};
    const float* Wp1 = (const float*)d_in[19];
    const float* bp1 = (const float*)d_in[20];
    const float* Wp2 = (const float*)d_in[21];
    const float* bp2 = (const float*)d_in[22];

    char* w = (char*)d_ws;
    auto alloc = [&](size_t bytes) {
        void* p = (void*)w;
        w += (bytes + 255) & ~(size_t)255;
        return p;
    };
    int* rowStart = (int*)alloc((NN + 1) * 4);
    int* cnt = (int*)alloc(NN * 4);
    int* cursor = (int*)alloc(NN * 4);
    int* part = (int*)alloc(128 * 4);
    int* gstart = (int*)alloc((NG + 1) * 4);
    float* pooled = (float*)alloc(NG * HD * 4);
    bf16* Wt = (bf16*)alloc(6 * 16384 * 2);
    int* sortedSrc = (int*)alloc((size_t)NE * 4);
    bf16* xb = (bf16*)alloc((size_t)NN * HD * 2);
    bf16* bufT = (bf16*)alloc((size_t)NN * HD * 2);
    bf16* bufH = (bf16*)alloc((size_t)NN * HD * 2);

    const int* srcIdx = ei;
    const int* dstIdx = ei + NE;
    const int NB = (NN + 1023) / 1024;  // 98

    // x -> bf16
    conv_kernel<<<(NN * HD / 8) / 256, 256, 0, stream>>>(x, xb);

    // CSR build
    zero_i32<<<(NN + 255) / 256, 256, 0, stream>>>(cnt, NN);
    hist_kernel<<<(NE + 255) / 256, 256, 0, stream>>>(dstIdx, cnt);
    scan_part<<<NB, 256, 0, stream>>>(cnt, part);
    scan_small<<<1, 64, 0, stream>>>(part, NB, rowStart);
    scan_write<<<NB, 256, 0, stream>>>(cnt, part, rowStart, cursor);
    scatter_kernel<<<(NE + 255) / 256, 256, 0, stream>>>(srcIdx, dstIdx, cursor, sortedSrc);

    // graph boundaries + weight prep (transpose + bf16 + swizzle)
    bounds_kernel<<<(NN + 255) / 256, 256, 0, stream>>>(batch, gstart);
    for (int l = 0; l < 3; ++l) {
        wprep<<<8, 256, 0, stream>>>(W1[l], Wt + (size_t)(2 * l) * 16384);
        wprep<<<8, 256, 0, stream>>>(W2[l], Wt + (size_t)(2 * l + 1) * 16384);
    }

    // layers
    const bf16* hp = xb;
    for (int l = 0; l < 3; ++l) {
        agg_kernel<<<(NN * 16 + 255) / 256, 256, 0, stream>>>(hp, rowStart, sortedSrc, bufT);
        int doln = (l < 2) ? 1 : 0;
        const float* g = (l < 2) ? GAM[l] : GAM[0];
        const float* be = (l < 2) ? BET[l] : BET[0];
        mlp_bf16<<<512, 256, 0, stream>>>(bufT, Wt + (size_t)(2 * l) * 16384, B1[l],
                                          Wt + (size_t)(2 * l + 1) * 16384, B2[l], g, be, doln,
                                          bufH);
        hp = bufH;
    }

    // pooling + head
    pool_g<<<NG, 256, 0, stream>>>(bufH, gstart, pooled);
    head_kernel<<<NG, 128, 0, stream>>>(pooled, Wp1, bp1, Wp2, bp2, (float*)d_out);
}

// Round 6
// 281.730 us; speedup vs baseline: 7.4221x; 1.1313x over previous
//
#include <hip/hip_runtime.h>
#include <hip/hip_bf16.h>

typedef __bf16 bf16;
typedef __bf16 v8bf __attribute__((ext_vector_type(8)));
typedef float v4f __attribute__((ext_vector_type(4)));

#define NN 100000
#define NE 600000
#define HD 128
#define NG 256
#define NB 98                    // ceil(NN/1024)
#define NCHUNK ((NN + 63) / 64)  // 1563

#define PREP_CONV 6250
#define PREP_ZERO 391
#define PREP_BNDS 391
#define PREP_W 48
#define PREP_TOTAL (PREP_CONV + PREP_ZERO + PREP_BNDS + PREP_W)  // 7080

static __device__ inline v8bf zero8() {
    v8bf z;
#pragma unroll
    for (int i = 0; i < 8; ++i) z[i] = (bf16)0.f;
    return z;
}

// ---- prep: conv(x->bf16) | zero cnt | graph bounds | weight prep (all 6) ----
__global__ void prep_kernel(const float* __restrict__ x, bf16* __restrict__ xb,
                            int* __restrict__ cnt, const int* __restrict__ batch,
                            int* __restrict__ gstart, const float* __restrict__ w10,
                            const float* __restrict__ w20, const float* __restrict__ w11,
                            const float* __restrict__ w21, const float* __restrict__ w12,
                            const float* __restrict__ w22, bf16* __restrict__ Wt) {
    int bid = blockIdx.x, tid = threadIdx.x;
    if (bid < PREP_CONV) {
        int i = bid * 256 + tid;  // one per 8 elems
        const v4f a = *(const v4f*)&x[(size_t)i * 8];
        const v4f b = *(const v4f*)&x[(size_t)i * 8 + 4];
        v8bf o;
#pragma unroll
        for (int q = 0; q < 4; ++q) {
            o[q] = (bf16)a[q];
            o[4 + q] = (bf16)b[q];
        }
        *(v8bf*)&xb[(size_t)i * 8] = o;
    } else if (bid < PREP_CONV + PREP_ZERO) {
        int i = (bid - PREP_CONV) * 256 + tid;
        if (i < NN) cnt[i] = 0;
    } else if (bid < PREP_CONV + PREP_ZERO + PREP_BNDS) {
        int n = (bid - PREP_CONV - PREP_ZERO) * 256 + tid;
        if (n < NN) {
            int b = batch[n];
            int prev = (n == 0) ? -1 : batch[n - 1];
            for (int g = prev + 1; g <= b; ++g) gstart[g] = n;
            if (n == NN - 1)
                for (int g = b + 1; g <= NG; ++g) gstart[g] = NN;
        }
    } else {
        int wb = bid - (PREP_CONV + PREP_ZERO + PREP_BNDS);  // 0..47
        int widx = wb >> 3;
        const float* W;
        switch (widx) {
            case 0: W = w10; break;
            case 1: W = w20; break;
            case 2: W = w11; break;
            case 3: W = w21; break;
            case 4: W = w12; break;
            default: W = w22; break;
        }
        bf16* dst = Wt + (size_t)widx * 16384;
        int c = (wb & 7) * 256 + tid;  // 0..2047
        int j = c >> 4, ck = c & 15;
        v8bf o;
#pragma unroll
        for (int q = 0; q < 8; ++q) o[q] = (bf16)W[(ck * 8 + q) * 128 + j];
        *(v8bf*)&dst[j * 128 + ((ck ^ (j & 15)) << 3)] = o;
    }
}

// ---------------- CSR build ----------------
__global__ void hist_kernel(const int* __restrict__ dst, int* __restrict__ cnt) {
    int e = blockIdx.x * blockDim.x + threadIdx.x;
    if (e < NE) atomicAdd(&cnt[dst[e]], 1);
}

__global__ void scan_part(const int* __restrict__ cnt, int* __restrict__ part) {
    __shared__ int red[256];
    int b = blockIdx.x, t = threadIdx.x;
    int base = b * 1024 + t * 4;
    int s = 0;
#pragma unroll
    for (int q = 0; q < 4; ++q) {
        int i = base + q;
        s += (i < NN) ? cnt[i] : 0;
    }
    red[t] = s;
    __syncthreads();
    for (int off = 128; off > 0; off >>= 1) {
        if (t < off) red[t] += red[t + off];
        __syncthreads();
    }
    if (t == 0) part[b] = red[0];
}

// scan_write: inline-scan the NB partials (no serial kernel), then per-thread scan
__global__ void scan_write(const int* __restrict__ cnt, const int* __restrict__ part,
                           int* __restrict__ rowStart, int* __restrict__ cursor) {
    __shared__ int tsum[256];
    __shared__ int psc[128];
    int b = blockIdx.x, t = threadIdx.x;
    if (t < 128) psc[t] = (t < NB) ? part[t] : 0;
    __syncthreads();
    for (int off = 1; off < 128; off <<= 1) {
        int v = (t < 128 && t >= off) ? psc[t - off] : 0;
        __syncthreads();
        if (t < 128) psc[t] += v;
        __syncthreads();
    }
    int blockoff = (b == 0) ? 0 : psc[b - 1];

    int base = b * 1024 + t * 4;
    int v[4];
    int s = 0;
#pragma unroll
    for (int q = 0; q < 4; ++q) {
        int i = base + q;
        v[q] = (i < NN) ? cnt[i] : 0;
        s += v[q];
    }
    tsum[t] = s;
    __syncthreads();
    for (int off = 1; off < 256; off <<= 1) {
        int x = (t >= off) ? tsum[t - off] : 0;
        __syncthreads();
        tsum[t] += x;
        __syncthreads();
    }
    int excl = tsum[t] - s + blockoff;
#pragma unroll
    for (int q = 0; q < 4; ++q) {
        int i = base + q;
        if (i < NN) {
            rowStart[i] = excl;
            cursor[i] = excl;
            excl += v[q];
        }
    }
    if (b == 0 && t == 0) rowStart[NN] = NE;
}

__global__ void scatter_kernel(const int* __restrict__ src, const int* __restrict__ dst,
                               int* __restrict__ cursor, int* __restrict__ sortedSrc) {
    int e = blockIdx.x * blockDim.x + threadIdx.x;
    if (e < NE) {
        int d = dst[e];
        int pos = atomicAdd(&cursor[d], 1);
        sortedSrc[pos] = src[e];
    }
}

// ---------------- aggregation: hin = h + sum_{src->i} h[src] ----------------
// 4 nodes per wave (16 lanes x 16B per row); 4-way software-pipelined gather.
__global__ void agg_kernel(const bf16* __restrict__ hprev, const int* __restrict__ rowStart,
                           const int* __restrict__ sortedSrc, bf16* __restrict__ hin) {
    int node = (blockIdx.x * blockDim.x + threadIdx.x) >> 4;
    if (node >= NN) return;
    int l16 = threadIdx.x & 15;
    int grp = (threadIdx.x & 63) >> 4;
    int s = rowStart[node], e = rowStart[node + 1];
    v8bf h = *(const v8bf*)&hprev[(size_t)node * HD + l16 * 8];
    float a[8];
#pragma unroll
    for (int q = 0; q < 8; ++q) a[q] = (float)h[q];
    for (int base = s; base < e; base += 16) {
        int cnt = e - base;
        if (cnt > 16) cnt = 16;
        int idx = (l16 < cnt) ? sortedSrc[base + l16] : 0;
        int i = 0;
        for (; i + 4 <= cnt; i += 4) {
            int sn0 = __shfl(idx, grp * 16 + i + 0, 64);
            int sn1 = __shfl(idx, grp * 16 + i + 1, 64);
            int sn2 = __shfl(idx, grp * 16 + i + 2, 64);
            int sn3 = __shfl(idx, grp * 16 + i + 3, 64);
            v8bf x0 = *(const v8bf*)&hprev[(size_t)sn0 * HD + l16 * 8];
            v8bf x1 = *(const v8bf*)&hprev[(size_t)sn1 * HD + l16 * 8];
            v8bf x2 = *(const v8bf*)&hprev[(size_t)sn2 * HD + l16 * 8];
            v8bf x3 = *(const v8bf*)&hprev[(size_t)sn3 * HD + l16 * 8];
#pragma unroll
            for (int q = 0; q < 8; ++q)
                a[q] += ((float)x0[q] + (float)x1[q]) + ((float)x2[q] + (float)x3[q]);
        }
        for (; i + 2 <= cnt; i += 2) {
            int sn0 = __shfl(idx, grp * 16 + i + 0, 64);
            int sn1 = __shfl(idx, grp * 16 + i + 1, 64);
            v8bf x0 = *(const v8bf*)&hprev[(size_t)sn0 * HD + l16 * 8];
            v8bf x1 = *(const v8bf*)&hprev[(size_t)sn1 * HD + l16 * 8];
#pragma unroll
            for (int q = 0; q < 8; ++q) a[q] += (float)x0[q] + (float)x1[q];
        }
        if (i < cnt) {
            int sn0 = __shfl(idx, grp * 16 + i, 64);
            v8bf x0 = *(const v8bf*)&hprev[(size_t)sn0 * HD + l16 * 8];
#pragma unroll
            for (int q = 0; q < 8; ++q) a[q] += (float)x0[q];
        }
    }
    v8bf o;
#pragma unroll
    for (int q = 0; q < 8; ++q) o[q] = (bf16)a[q];
    *(v8bf*)&hin[(size_t)node * HD + l16 * 8] = o;
}

// -------- fused MLP: persistent blocks, weights staged once in LDS --------
__global__ __launch_bounds__(256) void mlp_bf16(const bf16* __restrict__ hin,
                                                const bf16* __restrict__ W1s,
                                                const float* __restrict__ b1,
                                                const bf16* __restrict__ W2s,
                                                const float* __restrict__ b2,
                                                const float* __restrict__ gam,
                                                const float* __restrict__ bet, const int do_ln,
                                                bf16* __restrict__ hout) {
    __shared__ bf16 lw[2][128 * 128];  // swizzled W1^T, W2^T (64KB)
    __shared__ bf16 lT[4][16 * 128];   // per-wave intermediate tile (16KB)

    const int tid = threadIdx.x;
    for (int i = tid; i < 2048; i += 256) {
        *(v8bf*)&lw[0][i * 8] = *(const v8bf*)&W1s[i * 8];
        *(v8bf*)&lw[1][i * 8] = *(const v8bf*)&W2s[i * 8];
    }
    __syncthreads();

    const int wave = tid >> 6, lane = tid & 63;
    const int lrow = lane & 15, lg = lane >> 4;

    float bj1[8], bj2[8], gj[8], bb[8];
#pragma unroll
    for (int t = 0; t < 8; ++t) {
        bj1[t] = b1[t * 16 + lrow];
        bj2[t] = b2[t * 16 + lrow];
        gj[t] = gam[t * 16 + lrow];
        bb[t] = bet[t * 16 + lrow];
    }

    for (int chunk = blockIdx.x; chunk < NCHUNK; chunk += gridDim.x) {
        const int r0 = chunk * 64 + wave * 16;
        const int arow = r0 + lrow;
        const bool rowok = arow < NN;

        v4f acc[8];
#pragma unroll
        for (int t = 0; t < 8; ++t) acc[t] = (v4f){0.f, 0.f, 0.f, 0.f};
#pragma unroll
        for (int s = 0; s < 4; ++s) {
            v8bf a = rowok ? *(const v8bf*)&hin[(size_t)arow * HD + s * 32 + lg * 8] : zero8();
#pragma unroll
            for (int t = 0; t < 8; ++t) {
                int j = t * 16 + lrow;
                v8bf b = *(const v8bf*)&lw[0][j * 128 + (((s * 4 + lg) ^ (j & 15)) << 3)];
                acc[t] = __builtin_amdgcn_mfma_f32_16x16x32_bf16(a, b, acc[t], 0, 0, 0);
            }
        }
#pragma unroll
        for (int t = 0; t < 8; ++t) {
#pragma unroll
            for (int r = 0; r < 4; ++r) {
                float v = fmaxf(acc[t][r] + bj1[t], 0.f);
                int i = lg * 4 + r;
                int k2 = t * 16 + lrow;
                lT[wave][i * 128 + (((k2 >> 3) ^ i) << 3) + (k2 & 7)] = (bf16)v;
            }
        }
        v4f acc2[8];
#pragma unroll
        for (int t = 0; t < 8; ++t) acc2[t] = (v4f){0.f, 0.f, 0.f, 0.f};
#pragma unroll
        for (int s = 0; s < 4; ++s) {
            v8bf a = *(const v8bf*)&lT[wave][lrow * 128 + (((s * 4 + lg) ^ lrow) << 3)];
#pragma unroll
            for (int t = 0; t < 8; ++t) {
                int j = t * 16 + lrow;
                v8bf b = *(const v8bf*)&lw[1][j * 128 + (((s * 4 + lg) ^ (j & 15)) << 3)];
                acc2[t] = __builtin_amdgcn_mfma_f32_16x16x32_bf16(a, b, acc2[t], 0, 0, 0);
            }
        }
        float vout[8][4];
#pragma unroll
        for (int t = 0; t < 8; ++t) {
#pragma unroll
            for (int r = 0; r < 4; ++r) vout[t][r] = fmaxf(acc2[t][r] + bj2[t], 0.f);
        }
        if (do_ln) {
            float s1[4] = {0.f, 0.f, 0.f, 0.f}, s2[4] = {0.f, 0.f, 0.f, 0.f};
#pragma unroll
            for (int t = 0; t < 8; ++t)
#pragma unroll
                for (int r = 0; r < 4; ++r) {
                    float v = vout[t][r];
                    s1[r] += v;
                    s2[r] += v * v;
                }
#pragma unroll
            for (int m = 1; m < 16; m <<= 1) {
#pragma unroll
                for (int r = 0; r < 4; ++r) {
                    s1[r] += __shfl_xor(s1[r], m, 64);
                    s2[r] += __shfl_xor(s2[r], m, 64);
                }
            }
#pragma unroll
            for (int t = 0; t < 8; ++t) {
#pragma unroll
                for (int r = 0; r < 4; ++r) {
                    float mu = s1[r] * (1.f / 128.f);
                    float var = s2[r] * (1.f / 128.f) - mu * mu;
                    float rs = rsqrtf(var + 1e-5f);
                    vout[t][r] = (vout[t][r] - mu) * rs * gj[t] + bb[t];
                }
            }
        }
#pragma unroll
        for (int t = 0; t < 8; ++t)
#pragma unroll
            for (int r = 0; r < 4; ++r) {
                int row = r0 + lg * 4 + r;
                if (row < NN) hout[(size_t)row * HD + t * 16 + lrow] = (bf16)vout[t][r];
            }
    }
}

// ------- fused mean-pool + head: one block per graph, 256 threads -------
__global__ void poolhead_kernel(const bf16* __restrict__ h, const int* __restrict__ gstart,
                                const float* __restrict__ Wp1, const float* __restrict__ bp1,
                                const float* __restrict__ Wp2, const float* __restrict__ bp2,
                                float* __restrict__ out) {
    __shared__ float row[128];
    __shared__ float part[128];
    __shared__ float ph[256];
    __shared__ float r0s[128];
    __shared__ float r1s[128];
    int g = blockIdx.x;
    int t = threadIdx.x;
    int f = t & 127, half = t >> 7;
    int gs = gstart[g], ge = gstart[g + 1];

    // pool
    float acc = 0.f;
    int n = gs + half;
#pragma unroll 1
    for (; n + 6 < ge; n += 8) {
        float a0 = (float)h[(size_t)(n + 0) * HD + f];
        float a1 = (float)h[(size_t)(n + 2) * HD + f];
        float a2 = (float)h[(size_t)(n + 4) * HD + f];
        float a3 = (float)h[(size_t)(n + 6) * HD + f];
        acc += (a0 + a1) + (a2 + a3);
    }
    for (; n < ge; n += 2) acc += (float)h[(size_t)n * HD + f];
    if (half == 1) part[f] = acc;
    __syncthreads();
    if (half == 0) row[f] = (acc + part[f]) / fmaxf((float)(ge - gs), 1.f);
    __syncthreads();

    // head: matvec split over k-halves
    float p = (half == 0) ? bp1[f] : 0.f;
    int k0 = half * 64;
    for (int k = k0; k < k0 + 64; ++k) p += row[k] * Wp1[k * 128 + f];
    ph[t] = p;
    __syncthreads();
    if (t < 128) {
        float pf = ph[f] + ph[128 + f];
        r0s[f] = pf * Wp2[f * 2 + 0];
        r1s[f] = pf * Wp2[f * 2 + 1];
    }
    __syncthreads();
    for (int off = 64; off > 0; off >>= 1) {
        if (t < off) {
            r0s[t] += r0s[t + off];
            r1s[t] += r1s[t + off];
        }
        __syncthreads();
    }
    if (t == 0) {
        float e0 = r0s[0] + bp2[0];
        float e1 = r1s[0] + bp2[1];
        float m = fmaxf(e0, e1);
        float lse = m + logf(expf(e0 - m) + expf(e1 - m));
        out[g * 2 + 0] = e0;
        out[g * 2 + 1] = e1;
        out[NG * 2 + g * 2 + 0] = e0 - lse;
        out[NG * 2 + g * 2 + 1] = e1 - lse;
    }
}

extern "C" void kernel_launch(void* const* d_in, const int* in_sizes, int n_in, void* d_out,
                              int out_size, void* d_ws, size_t ws_size, hipStream_t stream) {
    const float* x = (const float*)d_in[0];
    const int* ei = (const int*)d_in[1];  // [2][E]: src row then dst row
    const int* batch = (const int*)d_in[2];
    const float* W1[3] = {(const float*)d_in[3], (const float*)d_in[7], (const float*)d_in[11]};
    const float* B1[3] = {(const float*)d_in[4], (const float*)d_in[8], (const float*)d_in[12]};
    const float* W2[3] = {(const float*)d_in[5], (const float*)d_in[9], (const float*)d_in[13]};
    const float* B2[3] = {(const float*)d_in[6], (const float*)d_in[10], (const float*)d_in[14]};
    const float* GAM[2] = {(const float*)d_in[15], (const float*)d_in[17]};
    const float* BET[2] = {(const float*)d_in[16], (const float*)d_in[18]};
    const float* Wp1 = (const float*)d_in[19];
    const float* bp1 = (const float*)d_in[20];
    const float* Wp2 = (const float*)d_in[21];
    const float* bp2 = (const float*)d_in[22];

    char* w = (char*)d_ws;
    auto alloc = [&](size_t bytes) {
        void* p = (void*)w;
        w += (bytes + 255) & ~(size_t)255;
        return p;
    };
    int* rowStart = (int*)alloc((NN + 1) * 4);
    int* cnt = (int*)alloc(NN * 4);
    int* cursor = (int*)alloc(NN * 4);
    int* part = (int*)alloc(128 * 4);
    int* gstart = (int*)alloc((NG + 1) * 4);
    bf16* Wt = (bf16*)alloc(6 * 16384 * 2);
    int* sortedSrc = (int*)alloc((size_t)NE * 4);
    bf16* xb = (bf16*)alloc((size_t)NN * HD * 2);
    bf16* bufT = (bf16*)alloc((size_t)NN * HD * 2);
    bf16* bufH = (bf16*)alloc((size_t)NN * HD * 2);

    const int* srcIdx = ei;
    const int* dstIdx = ei + NE;

    // prep: conv + zero(cnt) + bounds + all weight preps
    prep_kernel<<<PREP_TOTAL, 256, 0, stream>>>(x, xb, cnt, batch, gstart, W1[0], W2[0], W1[1],
                                                W2[1], W1[2], W2[2], Wt);
    // CSR build
    hist_kernel<<<(NE + 255) / 256, 256, 0, stream>>>(dstIdx, cnt);
    scan_part<<<NB, 256, 0, stream>>>(cnt, part);
    scan_write<<<NB, 256, 0, stream>>>(cnt, part, rowStart, cursor);
    scatter_kernel<<<(NE + 255) / 256, 256, 0, stream>>>(srcIdx, dstIdx, cursor, sortedSrc);

    // layers
    const bf16* hp = xb;
    for (int l = 0; l < 3; ++l) {
        agg_kernel<<<(NN * 16 + 255) / 256, 256, 0, stream>>>(hp, rowStart, sortedSrc, bufT);
        int doln = (l < 2) ? 1 : 0;
        const float* g = (l < 2) ? GAM[l] : GAM[0];
        const float* be = (l < 2) ? BET[l] : BET[0];
        mlp_bf16<<<512, 256, 0, stream>>>(bufT, Wt + (size_t)(2 * l) * 16384, B1[l],
                                          Wt + (size_t)(2 * l + 1) * 16384, B2[l], g, be, doln,
                                          bufH);
        hp = bufH;
    }

    // fused pooling + head
    poolhead_kernel<<<NG, 256, 0, stream>>>(bufH, gstart, Wp1, bp1, Wp2, bp2, (float*)d_out);
}

// Round 7
// 278.465 us; speedup vs baseline: 7.5091x; 1.0117x over previous
//
#include <hip/hip_runtime.h>
#include <hip/hip_bf16.h>

typedef __bf16 bf16;
typedef __bf16 v8bf __attribute__((ext_vector_type(8)));
typedef float v4f __attribute__((ext_vector_type(4)));

#define NN 100000
#define NE 600000
#define HD 128
#define NG 256
#define NB 98                    // ceil(NN/1024)
#define NCHUNK ((NN + 63) / 64)  // 1563

#define PREP_CONV 6250
#define PREP_ZERO 391
#define PREP_BNDS 391
#define PREP_W 48
#define PREP_TOTAL (PREP_CONV + PREP_ZERO + PREP_BNDS + PREP_W)  // 7080

// ---- prep: conv(x->bf16) | zero cnt | graph bounds | weight prep (all 6) ----
__global__ void prep_kernel(const float* __restrict__ x, bf16* __restrict__ xb,
                            int* __restrict__ cnt, const int* __restrict__ batch,
                            int* __restrict__ gstart, const float* __restrict__ w10,
                            const float* __restrict__ w20, const float* __restrict__ w11,
                            const float* __restrict__ w21, const float* __restrict__ w12,
                            const float* __restrict__ w22, bf16* __restrict__ Wt) {
    int bid = blockIdx.x, tid = threadIdx.x;
    if (bid < PREP_CONV) {
        int i = bid * 256 + tid;  // one per 8 elems
        const v4f a = *(const v4f*)&x[(size_t)i * 8];
        const v4f b = *(const v4f*)&x[(size_t)i * 8 + 4];
        v8bf o;
#pragma unroll
        for (int q = 0; q < 4; ++q) {
            o[q] = (bf16)a[q];
            o[4 + q] = (bf16)b[q];
        }
        *(v8bf*)&xb[(size_t)i * 8] = o;
    } else if (bid < PREP_CONV + PREP_ZERO) {
        int i = (bid - PREP_CONV) * 256 + tid;
        if (i < NN) cnt[i] = 0;
    } else if (bid < PREP_CONV + PREP_ZERO + PREP_BNDS) {
        int n = (bid - PREP_CONV - PREP_ZERO) * 256 + tid;
        if (n < NN) {
            int b = batch[n];
            int prev = (n == 0) ? -1 : batch[n - 1];
            for (int g = prev + 1; g <= b; ++g) gstart[g] = n;
            if (n == NN - 1)
                for (int g = b + 1; g <= NG; ++g) gstart[g] = NN;
        }
    } else {
        int wb = bid - (PREP_CONV + PREP_ZERO + PREP_BNDS);  // 0..47
        int widx = wb >> 3;
        const float* W;
        switch (widx) {
            case 0: W = w10; break;
            case 1: W = w20; break;
            case 2: W = w11; break;
            case 3: W = w21; break;
            case 4: W = w12; break;
            default: W = w22; break;
        }
        bf16* dst = Wt + (size_t)widx * 16384;
        int c = (wb & 7) * 256 + tid;  // 0..2047
        int j = c >> 4, ck = c & 15;
        v8bf o;
#pragma unroll
        for (int q = 0; q < 8; ++q) o[q] = (bf16)W[(ck * 8 + q) * 128 + j];
        *(v8bf*)&dst[j * 128 + ((ck ^ (j & 15)) << 3)] = o;
    }
}

// ---------------- CSR build ----------------
__global__ void hist_kernel(const int* __restrict__ dst, int* __restrict__ cnt) {
    int e = blockIdx.x * blockDim.x + threadIdx.x;
    if (e < NE) atomicAdd(&cnt[dst[e]], 1);
}

__global__ void scan_part(const int* __restrict__ cnt, int* __restrict__ part) {
    __shared__ int red[256];
    int b = blockIdx.x, t = threadIdx.x;
    int base = b * 1024 + t * 4;
    int s = 0;
#pragma unroll
    for (int q = 0; q < 4; ++q) {
        int i = base + q;
        s += (i < NN) ? cnt[i] : 0;
    }
    red[t] = s;
    __syncthreads();
    for (int off = 128; off > 0; off >>= 1) {
        if (t < off) red[t] += red[t + off];
        __syncthreads();
    }
    if (t == 0) part[b] = red[0];
}

// scan_write: inline-scan the NB partials, then per-thread scan
__global__ void scan_write(const int* __restrict__ cnt, const int* __restrict__ part,
                           int* __restrict__ rowStart, int* __restrict__ cursor) {
    __shared__ int tsum[256];
    __shared__ int psc[128];
    int b = blockIdx.x, t = threadIdx.x;
    if (t < 128) psc[t] = (t < NB) ? part[t] : 0;
    __syncthreads();
    for (int off = 1; off < 128; off <<= 1) {
        int v = (t < 128 && t >= off) ? psc[t - off] : 0;
        __syncthreads();
        if (t < 128) psc[t] += v;
        __syncthreads();
    }
    int blockoff = (b == 0) ? 0 : psc[b - 1];

    int base = b * 1024 + t * 4;
    int v[4];
    int s = 0;
#pragma unroll
    for (int q = 0; q < 4; ++q) {
        int i = base + q;
        v[q] = (i < NN) ? cnt[i] : 0;
        s += v[q];
    }
    tsum[t] = s;
    __syncthreads();
    for (int off = 1; off < 256; off <<= 1) {
        int x = (t >= off) ? tsum[t - off] : 0;
        __syncthreads();
        tsum[t] += x;
        __syncthreads();
    }
    int excl = tsum[t] - s + blockoff;
#pragma unroll
    for (int q = 0; q < 4; ++q) {
        int i = base + q;
        if (i < NN) {
            rowStart[i] = excl;
            cursor[i] = excl;
            excl += v[q];
        }
    }
    if (b == 0 && t == 0) rowStart[NN] = NE;
}

__global__ void scatter_kernel(const int* __restrict__ src, const int* __restrict__ dst,
                               int* __restrict__ cursor, int* __restrict__ sortedSrc) {
    int e = blockIdx.x * blockDim.x + threadIdx.x;
    if (e < NE) {
        int d = dst[e];
        int pos = atomicAdd(&cursor[d], 1);
        sortedSrc[pos] = src[e];
    }
}

// ---- fused GIN layer: gather(agg) -> MLP(GEMM1,relu,GEMM2) -> [LN] -> store ----
// Per-wave 16-row tile. Gather writes rows into per-wave LDS tile in the
// XOR-swizzled A-fragment layout; tile is then reused for the relu intermediate.
__global__ __launch_bounds__(256) void gin_layer(
    const bf16* __restrict__ hprev, const int* __restrict__ rowStart,
    const int* __restrict__ sortedSrc, const bf16* __restrict__ W1s,
    const float* __restrict__ b1, const bf16* __restrict__ W2s, const float* __restrict__ b2,
    const float* __restrict__ gam, const float* __restrict__ bet, const int do_ln,
    bf16* __restrict__ hout) {
    __shared__ bf16 lw[2][128 * 128];  // swizzled W1^T, W2^T (64KB)
    __shared__ bf16 tile[4][16 * 128]; // per-wave: hin tile, then relu tile (16KB)

    const int tid = threadIdx.x;
    for (int i = tid; i < 2048; i += 256) {
        *(v8bf*)&lw[0][i * 8] = *(const v8bf*)&W1s[i * 8];
        *(v8bf*)&lw[1][i * 8] = *(const v8bf*)&W2s[i * 8];
    }
    __syncthreads();

    const int wave = tid >> 6, lane = tid & 63;
    const int lrow = lane & 15, lg = lane >> 4;

    float bj1[8], bj2[8], gj[8], bb[8];
#pragma unroll
    for (int t = 0; t < 8; ++t) {
        bj1[t] = b1[t * 16 + lrow];
        bj2[t] = b2[t * 16 + lrow];
        gj[t] = gam[t * 16 + lrow];
        bb[t] = bet[t * 16 + lrow];
    }

    for (int chunk = blockIdx.x; chunk < NCHUNK; chunk += gridDim.x) {
        const int r0 = chunk * 64 + wave * 16;

        // ---- per-lane rowStart loads for the 16 tile rows (+1)
        int rsi = r0 + lrow;
        if (rsi > NN) rsi = NN;
        int rei = r0 + lrow + 1;
        if (rei > NN) rei = NN;
        int rs = rowStart[rsi], re = rowStart[rei];

        // ---- gather: group lg handles local rows lg*4 .. lg*4+3
#pragma unroll 1
        for (int j = lg * 4; j < lg * 4 + 4; ++j) {
            int nd = r0 + j;
            int s = __shfl(rs, j, 64);
            int e = __shfl(re, j, 64);
            float a[8];
            if (nd < NN) {
                v8bf h = *(const v8bf*)&hprev[(size_t)nd * HD + lrow * 8];
#pragma unroll
                for (int q = 0; q < 8; ++q) a[q] = (float)h[q];
            } else {
#pragma unroll
                for (int q = 0; q < 8; ++q) a[q] = 0.f;
            }
            for (int base = s; base < e; base += 16) {
                int cnt = e - base;
                if (cnt > 16) cnt = 16;
                int idx = (lrow < cnt) ? sortedSrc[base + lrow] : 0;
                int i = 0;
                for (; i + 4 <= cnt; i += 4) {
                    int sn0 = __shfl(idx, lg * 16 + i + 0, 64);
                    int sn1 = __shfl(idx, lg * 16 + i + 1, 64);
                    int sn2 = __shfl(idx, lg * 16 + i + 2, 64);
                    int sn3 = __shfl(idx, lg * 16 + i + 3, 64);
                    v8bf x0 = *(const v8bf*)&hprev[(size_t)sn0 * HD + lrow * 8];
                    v8bf x1 = *(const v8bf*)&hprev[(size_t)sn1 * HD + lrow * 8];
                    v8bf x2 = *(const v8bf*)&hprev[(size_t)sn2 * HD + lrow * 8];
                    v8bf x3 = *(const v8bf*)&hprev[(size_t)sn3 * HD + lrow * 8];
#pragma unroll
                    for (int q = 0; q < 8; ++q)
                        a[q] += ((float)x0[q] + (float)x1[q]) + ((float)x2[q] + (float)x3[q]);
                }
                for (; i + 2 <= cnt; i += 2) {
                    int sn0 = __shfl(idx, lg * 16 + i + 0, 64);
                    int sn1 = __shfl(idx, lg * 16 + i + 1, 64);
                    v8bf x0 = *(const v8bf*)&hprev[(size_t)sn0 * HD + lrow * 8];
                    v8bf x1 = *(const v8bf*)&hprev[(size_t)sn1 * HD + lrow * 8];
#pragma unroll
                    for (int q = 0; q < 8; ++q) a[q] += (float)x0[q] + (float)x1[q];
                }
                if (i < cnt) {
                    int sn0 = __shfl(idx, lg * 16 + i, 64);
                    v8bf x0 = *(const v8bf*)&hprev[(size_t)sn0 * HD + lrow * 8];
#pragma unroll
                    for (int q = 0; q < 8; ++q) a[q] += (float)x0[q];
                }
            }
            // write row j into tile (lane holds chunk lrow), swizzled: chunk ck at ((ck^j)<<3)
            v8bf o;
#pragma unroll
            for (int q = 0; q < 8; ++q) o[q] = (bf16)a[q];
            *(v8bf*)&tile[wave][j * 128 + ((lrow ^ j) << 3)] = o;
        }

        // ---- GEMM1: acc[t] = hin_tile @ W1 (A from tile, B from LDS)
        v4f acc[8];
#pragma unroll
        for (int t = 0; t < 8; ++t) acc[t] = (v4f){0.f, 0.f, 0.f, 0.f};
#pragma unroll
        for (int s = 0; s < 4; ++s) {
            v8bf a = *(const v8bf*)&tile[wave][lrow * 128 + (((s * 4 + lg) ^ lrow) << 3)];
#pragma unroll
            for (int t = 0; t < 8; ++t) {
                int j = t * 16 + lrow;
                v8bf b = *(const v8bf*)&lw[0][j * 128 + (((s * 4 + lg) ^ (j & 15)) << 3)];
                acc[t] = __builtin_amdgcn_mfma_f32_16x16x32_bf16(a, b, acc[t], 0, 0, 0);
            }
        }
        // ---- bias + relu -> tile (overwrite, same swizzle)
#pragma unroll
        for (int t = 0; t < 8; ++t) {
#pragma unroll
            for (int r = 0; r < 4; ++r) {
                float v = fmaxf(acc[t][r] + bj1[t], 0.f);
                int i = lg * 4 + r;
                int k2 = t * 16 + lrow;
                tile[wave][i * 128 + (((k2 >> 3) ^ i) << 3) + (k2 & 7)] = (bf16)v;
            }
        }
        // ---- GEMM2
        v4f acc2[8];
#pragma unroll
        for (int t = 0; t < 8; ++t) acc2[t] = (v4f){0.f, 0.f, 0.f, 0.f};
#pragma unroll
        for (int s = 0; s < 4; ++s) {
            v8bf a = *(const v8bf*)&tile[wave][lrow * 128 + (((s * 4 + lg) ^ lrow) << 3)];
#pragma unroll
            for (int t = 0; t < 8; ++t) {
                int j = t * 16 + lrow;
                v8bf b = *(const v8bf*)&lw[1][j * 128 + (((s * 4 + lg) ^ (j & 15)) << 3)];
                acc2[t] = __builtin_amdgcn_mfma_f32_16x16x32_bf16(a, b, acc2[t], 0, 0, 0);
            }
        }
        // ---- epilogue: bias + relu (+ LN) + store
        float vout[8][4];
#pragma unroll
        for (int t = 0; t < 8; ++t) {
#pragma unroll
            for (int r = 0; r < 4; ++r) vout[t][r] = fmaxf(acc2[t][r] + bj2[t], 0.f);
        }
        if (do_ln) {
            float s1[4] = {0.f, 0.f, 0.f, 0.f}, s2[4] = {0.f, 0.f, 0.f, 0.f};
#pragma unroll
            for (int t = 0; t < 8; ++t)
#pragma unroll
                for (int r = 0; r < 4; ++r) {
                    float v = vout[t][r];
                    s1[r] += v;
                    s2[r] += v * v;
                }
#pragma unroll
            for (int m = 1; m < 16; m <<= 1) {
#pragma unroll
                for (int r = 0; r < 4; ++r) {
                    s1[r] += __shfl_xor(s1[r], m, 64);
                    s2[r] += __shfl_xor(s2[r], m, 64);
                }
            }
#pragma unroll
            for (int t = 0; t < 8; ++t) {
#pragma unroll
                for (int r = 0; r < 4; ++r) {
                    float mu = s1[r] * (1.f / 128.f);
                    float var = s2[r] * (1.f / 128.f) - mu * mu;
                    float rs2 = rsqrtf(var + 1e-5f);
                    vout[t][r] = (vout[t][r] - mu) * rs2 * gj[t] + bb[t];
                }
            }
        }
#pragma unroll
        for (int t = 0; t < 8; ++t)
#pragma unroll
            for (int r = 0; r < 4; ++r) {
                int row = r0 + lg * 4 + r;
                if (row < NN) hout[(size_t)row * HD + t * 16 + lrow] = (bf16)vout[t][r];
            }
    }
}

// ------- fused mean-pool + head: one block per graph, 256 threads -------
__global__ void poolhead_kernel(const bf16* __restrict__ h, const int* __restrict__ gstart,
                                const float* __restrict__ Wp1, const float* __restrict__ bp1,
                                const float* __restrict__ Wp2, const float* __restrict__ bp2,
                                float* __restrict__ out) {
    __shared__ float row[128];
    __shared__ float part[128];
    __shared__ float ph[256];
    __shared__ float r0s[128];
    __shared__ float r1s[128];
    int g = blockIdx.x;
    int t = threadIdx.x;
    int f = t & 127, half = t >> 7;
    int gs = gstart[g], ge = gstart[g + 1];

    float acc = 0.f;
    int n = gs + half;
#pragma unroll 1
    for (; n + 6 < ge; n += 8) {
        float a0 = (float)h[(size_t)(n + 0) * HD + f];
        float a1 = (float)h[(size_t)(n + 2) * HD + f];
        float a2 = (float)h[(size_t)(n + 4) * HD + f];
        float a3 = (float)h[(size_t)(n + 6) * HD + f];
        acc += (a0 + a1) + (a2 + a3);
    }
    for (; n < ge; n += 2) acc += (float)h[(size_t)n * HD + f];
    if (half == 1) part[f] = acc;
    __syncthreads();
    if (half == 0) row[f] = (acc + part[f]) / fmaxf((float)(ge - gs), 1.f);
    __syncthreads();

    float p = (half == 0) ? bp1[f] : 0.f;
    int k0 = half * 64;
    for (int k = k0; k < k0 + 64; ++k) p += row[k] * Wp1[k * 128 + f];
    ph[t] = p;
    __syncthreads();
    if (t < 128) {
        float pf = ph[f] + ph[128 + f];
        r0s[f] = pf * Wp2[f * 2 + 0];
        r1s[f] = pf * Wp2[f * 2 + 1];
    }
    __syncthreads();
    for (int off = 64; off > 0; off >>= 1) {
        if (t < off) {
            r0s[t] += r0s[t + off];
            r1s[t] += r1s[t + off];
        }
        __syncthreads();
    }
    if (t == 0) {
        float e0 = r0s[0] + bp2[0];
        float e1 = r1s[0] + bp2[1];
        float m = fmaxf(e0, e1);
        float lse = m + logf(expf(e0 - m) + expf(e1 - m));
        out[g * 2 + 0] = e0;
        out[g * 2 + 1] = e1;
        out[NG * 2 + g * 2 + 0] = e0 - lse;
        out[NG * 2 + g * 2 + 1] = e1 - lse;
    }
}

extern "C" void kernel_launch(void* const* d_in, const int* in_sizes, int n_in, void* d_out,
                              int out_size, void* d_ws, size_t ws_size, hipStream_t stream) {
    const float* x = (const float*)d_in[0];
    const int* ei = (const int*)d_in[1];  // [2][E]: src row then dst row
    const int* batch = (const int*)d_in[2];
    const float* W1[3] = {(const float*)d_in[3], (const float*)d_in[7], (const float*)d_in[11]};
    const float* B1[3] = {(const float*)d_in[4], (const float*)d_in[8], (const float*)d_in[12]};
    const float* W2[3] = {(const float*)d_in[5], (const float*)d_in[9], (const float*)d_in[13]};
    const float* B2[3] = {(const float*)d_in[6], (const float*)d_in[10], (const float*)d_in[14]};
    const float* GAM[2] = {(const float*)d_in[15], (const float*)d_in[17]};
    const float* BET[2] = {(const float*)d_in[16], (const float*)d_in[18]};
    const float* Wp1 = (const float*)d_in[19];
    const float* bp1 = (const float*)d_in[20];
    const float* Wp2 = (const float*)d_in[21];
    const float* bp2 = (const float*)d_in[22];

    char* w = (char*)d_ws;
    auto alloc = [&](size_t bytes) {
        void* p = (void*)w;
        w += (bytes + 255) & ~(size_t)255;
        return p;
    };
    int* rowStart = (int*)alloc((NN + 1) * 4);
    int* cnt = (int*)alloc(NN * 4);
    int* cursor = (int*)alloc(NN * 4);
    int* part = (int*)alloc(128 * 4);
    int* gstart = (int*)alloc((NG + 1) * 4);
    bf16* Wt = (bf16*)alloc(6 * 16384 * 2);
    int* sortedSrc = (int*)alloc((size_t)NE * 4);
    bf16* xb = (bf16*)alloc((size_t)NN * HD * 2);
    bf16* bufH = (bf16*)alloc((size_t)NN * HD * 2);

    const int* srcIdx = ei;
    const int* dstIdx = ei + NE;

    // prep: conv + zero(cnt) + bounds + all weight preps
    prep_kernel<<<PREP_TOTAL, 256, 0, stream>>>(x, xb, cnt, batch, gstart, W1[0], W2[0], W1[1],
                                                W2[1], W1[2], W2[2], Wt);
    // CSR build
    hist_kernel<<<(NE + 255) / 256, 256, 0, stream>>>(dstIdx, cnt);
    scan_part<<<NB, 256, 0, stream>>>(cnt, part);
    scan_write<<<NB, 256, 0, stream>>>(cnt, part, rowStart, cursor);
    scatter_kernel<<<(NE + 255) / 256, 256, 0, stream>>>(srcIdx, dstIdx, cursor, sortedSrc);

    // fused layers (agg + MLP)
    const bf16* hp = xb;
    for (int l = 0; l < 3; ++l) {
        int doln = (l < 2) ? 1 : 0;
        const float* g = (l < 2) ? GAM[l] : GAM[0];
        const float* be = (l < 2) ? BET[l] : BET[0];
        gin_layer<<<512, 256, 0, stream>>>(hp, rowStart, sortedSrc,
                                           Wt + (size_t)(2 * l) * 16384, B1[l],
                                           Wt + (size_t)(2 * l + 1) * 16384, B2[l], g, be, doln,
                                           bufH);
        hp = bufH;
    }

    // fused pooling + head
    poolhead_kernel<<<NG, 256, 0, stream>>>(bufH, gstart, Wp1, bp1, Wp2, bp2, (float*)d_out);
}